// Round 6
// baseline (7979.707 us; speedup 1.0000x reference)
//
#include <hip/hip_runtime.h>
#include <math.h>

#define NB 128
#define NP 196
#define NENC 2048
#define NE 512
#define ND 512
#define NA 512
#define NV 10000
#define NVPAD 10112
#define NL 52
#define NT 51
#define KXH2 2560   // [attw 2048 | h 512]

typedef unsigned short u16;
typedef __attribute__((ext_vector_type(8))) short bf16x8;
typedef __attribute__((ext_vector_type(8))) unsigned short u16x8;
typedef __attribute__((ext_vector_type(4))) float f32x4;

#define MFMA16 __builtin_amdgcn_mfma_f32_16x16x32_bf16

__device__ __forceinline__ float sigmoidf_(float v) { return 1.0f / (1.0f + __expf(-v)); }
__device__ __forceinline__ float b2f(u16 u) { return __uint_as_float(((unsigned int)u) << 16); }
__device__ __forceinline__ u16 f2b(float f) {
  unsigned int u = __float_as_uint(f);
  unsigned int r = (u + 0x7FFFu + ((u >> 16) & 1u)) >> 16;
  return (u16)r;
}

// ---------------- two-level grid barrier (monotonic epochs) ----------------
__device__ __forceinline__ void gsync(unsigned int* bar, int bid, int k) {
  __syncthreads();
  if (threadIdx.x == 0) {
    __threadfence();
    int g = bid & 7;
    unsigned int prev = __hip_atomic_fetch_add(&bar[g * 16], 1u, __ATOMIC_ACQ_REL,
                                               __HIP_MEMORY_SCOPE_AGENT);
    if (prev == (unsigned int)(k * 32 + 31)) {
      unsigned int pr = __hip_atomic_fetch_add(&bar[128], 1u, __ATOMIC_ACQ_REL,
                                               __HIP_MEMORY_SCOPE_AGENT);
      if (pr == (unsigned int)(k * 8 + 7)) {
        __hip_atomic_store(&bar[160], (unsigned int)(k + 1), __ATOMIC_RELEASE,
                           __HIP_MEMORY_SCOPE_AGENT);
      }
    }
    while (__hip_atomic_load(&bar[160], __ATOMIC_RELAXED, __HIP_MEMORY_SCOPE_AGENT)
           < (unsigned int)(k + 1)) {
      __builtin_amdgcn_s_sleep(2);
    }
    __threadfence();
  }
  __syncthreads();
}

// ---------------- sort + nact ----------------
__global__ void kSort(const int* __restrict__ cap_len, const int* __restrict__ captions,
                      int* __restrict__ order, int* __restrict__ nact,
                      float* __restrict__ out_cap, float* __restrict__ out_dlen) {
  __shared__ int lens[NB];
  __shared__ int s_dl[NB];
  int tid = threadIdx.x;
  lens[tid] = cap_len[tid];
  __syncthreads();
  int li = lens[tid];
  int r = 0;
  for (int j = 0; j < NB; ++j) {
    int lj = lens[j];
    if (lj > li || (lj == li && j < tid)) r++;
  }
  order[r] = tid;
  s_dl[r] = li - 1;
  out_dlen[r] = (float)(li - 1);
  for (int l = 0; l < NL; ++l)
    out_cap[(size_t)r * NL + l] = (float)captions[(size_t)tid * NL + l];
  __syncthreads();
  if (tid < NT) {
    int cnt = 0;
    for (int j = 0; j < NB; ++j) cnt += (s_dl[j] > tid) ? 1 : 0;
    nact[tid] = cnt;
  }
}

__global__ void kAlphaZero(const int* __restrict__ nact, float* __restrict__ out_alph) {
  int t = blockIdx.x;
  int n0 = nact[t];
  int cnt = (NB - n0) * NP;
  for (int i = threadIdx.x; i < cnt; i += 256) {
    int b = n0 + i / NP;
    int p = i - (i / NP) * NP;
    out_alph[((size_t)b * NT + t) * NP + p] = 0.0f;
  }
}

// ---------------- features gather + bf16 ----------------
__global__ void kFeats(const float* __restrict__ features, const int* __restrict__ order,
                       u16* __restrict__ featsb) {
  int p = blockIdx.x, b = blockIdx.y, tid = threadIdx.x;
  const float* src = features + ((size_t)order[b] * NP + p) * NENC + tid * 8;
  u16* dst = featsb + ((size_t)b * NP + p) * NENC + tid * 8;
  float4 v0 = *(const float4*)src;
  float4 v1 = *(const float4*)(src + 4);
  u16x8 o;
  o[0] = f2b(v0.x); o[1] = f2b(v0.y); o[2] = f2b(v0.z); o[3] = f2b(v0.w);
  o[4] = f2b(v1.x); o[5] = f2b(v1.y); o[6] = f2b(v1.z); o[7] = f2b(v1.w);
  *(u16x8*)dst = o;
}

// ---------------- weight transposes ----------------
__global__ void kTWenc(const float* __restrict__ W, u16* __restrict__ dst) {
  int n = blockIdx.x;
  for (int k = threadIdx.x; k < NENC; k += 256)
    dst[(size_t)n * NENC + k] = f2b(W[(size_t)k * NA + n]);
}
__global__ void kTdg(const float* __restrict__ Wdec, const float* __restrict__ Wbeta,
                     u16* __restrict__ dst) {
  int n = blockIdx.x;  // 2560
  for (int k = threadIdx.x; k < ND; k += 256) {
    float v = (n < NA) ? Wdec[(size_t)k * NA + n] : Wbeta[(size_t)k * NENC + (n - NA)];
    dst[(size_t)n * ND + k] = f2b(v);
  }
}
__global__ void kTWihTop(const float* __restrict__ Wih, u16* __restrict__ dst) {
  int n = blockIdx.x;  // 2048, col interleaved n = d*4+g
  int col = (n & 3) * ND + (n >> 2);
  for (int k = threadIdx.x; k < NE; k += 256)
    dst[(size_t)n * NE + k] = f2b(Wih[(size_t)k * (4 * ND) + col]);
}
__global__ void kTifgo2(const float* __restrict__ Wih, const float* __restrict__ Whh,
                        u16* __restrict__ dst) {
  int n = blockIdx.x;  // 2048
  int col = (n & 3) * ND + (n >> 2);
  for (int k = threadIdx.x; k < KXH2; k += 256) {
    float v = (k < NENC) ? Wih[(size_t)(NE + k) * (4 * ND) + col]
                         : Whh[(size_t)(k - NENC) * (4 * ND) + col];
    dst[(size_t)n * KXH2 + k] = f2b(v);
  }
}
__global__ void kTfc(const float* __restrict__ Wfc, u16* __restrict__ dst) {
  int n = blockIdx.x;  // NVPAD
  for (int k = threadIdx.x; k < ND; k += 256) {
    float v = (n < NV) ? Wfc[(size_t)k * NV + n] : 0.0f;
    dst[(size_t)n * ND + k] = f2b(v);
  }
}

// ---------------- embA: gather caption embeddings (bf16) ----------------
__global__ void kEmbA(const float* __restrict__ emb, const int* __restrict__ captions,
                      const int* __restrict__ order, u16* __restrict__ embA) {
  int t = blockIdx.x, b = blockIdx.y;
  int tok = captions[(size_t)order[b] * NL + t];
  int i = threadIdx.x * 2;
  float2 v = *(const float2*)(emb + (size_t)tok * NE + i);
  unsigned int w0 = (unsigned int)f2b(v.x) | ((unsigned int)f2b(v.y) << 16);
  *(unsigned int*)(embA + ((size_t)t * NB + b) * NE + i) = w0;
}

// ---------------- embAll = embA @ WihTopT (bf16 out, K=512) ----------------
__global__ __launch_bounds__(256) void kEmbGemm(const u16* __restrict__ A,
                                                const u16* __restrict__ BT,
                                                u16* __restrict__ D) {
  int w = threadIdx.x >> 6, lane = threadIdx.x & 63;
  int lr = lane & 15, lg = lane >> 4;
  int mb = blockIdx.y * 128 + w * 32;
  int nb = blockIdx.x * 64;
  f32x4 acc[2][4] = {};
  const u16* a0 = A + (size_t)(mb + lr) * NE + lg * 8;
  const u16* a1 = a0 + 16 * NE;
  const u16* b0 = BT + (size_t)(nb + lr) * NE + lg * 8;
  for (int k0 = 0; k0 < NE; k0 += 32) {
    bf16x8 af0 = *(const bf16x8*)(a0 + k0);
    bf16x8 af1 = *(const bf16x8*)(a1 + k0);
#pragma unroll
    for (int nt = 0; nt < 4; ++nt) {
      bf16x8 bf = *(const bf16x8*)(b0 + (size_t)nt * 16 * NE + k0);
      acc[0][nt] = MFMA16(af0, bf, acc[0][nt], 0, 0, 0);
      acc[1][nt] = MFMA16(af1, bf, acc[1][nt], 0, 0, 0);
    }
  }
#pragma unroll
  for (int mt = 0; mt < 2; ++mt)
#pragma unroll
    for (int nt = 0; nt < 4; ++nt)
#pragma unroll
      for (int j = 0; j < 4; ++j) {
        int row = mb + mt * 16 + lg * 4 + j;
        int col = nb + nt * 16 + lr;
        D[(size_t)row * NENC + col] = f2b(acc[mt][nt][j]);
      }
}

// ---------------- eo = mean over P ----------------
__global__ void kEo(const u16* __restrict__ featsb, float* __restrict__ eo) {
  int e = blockIdx.x * 256 + threadIdx.x;
  int b = blockIdx.y;
  const u16* f = featsb + (size_t)b * NP * NENC + e;
  float s = 0.0f;
  for (int p = 0; p < NP; ++p) s += b2f(f[(size_t)p * NENC]);
  eo[(size_t)b * NENC + e] = s * (1.0f / NP);
}

// ---------------- h0 / c0 ----------------
__global__ void kInitHC(const float* __restrict__ eo,
                        const float* __restrict__ W_h0, const float* __restrict__ b_h0,
                        const float* __restrict__ W_c0, const float* __restrict__ b_c0,
                        u16* __restrict__ hb, u16* __restrict__ xh0, float* __restrict__ c) {
  __shared__ float s_eo[NENC];
  int b = blockIdx.y;
  for (int i = threadIdx.x; i < NENC; i += 256) s_eo[i] = eo[(size_t)b * NENC + i];
  __syncthreads();
  int d = blockIdx.x * 256 + threadIdx.x;
  const float* W = blockIdx.z ? W_c0 : W_h0;
  const float* bias = blockIdx.z ? b_c0 : b_h0;
  float acc = bias[d];
  for (int k = 0; k < NENC; ++k) acc += s_eo[k] * W[(size_t)k * ND + d];
  if (blockIdx.z) {
    c[(size_t)b * ND + d] = acc;
  } else {
    u16 hv = f2b(acc);
    hb[(size_t)b * ND + d] = hv;
    xh0[(size_t)b * KXH2 + NENC + d] = hv;
  }
}

// ---------------- enc_proj (MFMA, 2-deep prefetch) ----------------
__global__ __launch_bounds__(256) void kEncProj(const u16* __restrict__ A,
                                                const u16* __restrict__ BT,
                                                const float* __restrict__ bias,
                                                u16* __restrict__ D) {
  int bid = blockIdx.x;
  int cc = bid & 7;
  int k = bid >> 3;
  int mt = cc * 25 + (k >> 3);
  if (mt >= 196) return;
  int ntile = k & 7;
  int w = threadIdx.x >> 6, lane = threadIdx.x & 63;
  int lr = lane & 15, lg = lane >> 4;
  int mb = mt * 128 + w * 32;
  int nb = ntile * 64;
  f32x4 acc[2][4] = {};
  const u16* a0 = A + (size_t)(mb + lr) * NENC + lg * 8;
  const u16* a1 = a0 + 16 * NENC;
  const u16* b0 = BT + (size_t)(nb + lr) * NENC + lg * 8;
  bf16x8 c0 = *(const bf16x8*)(a0);
  bf16x8 c1 = *(const bf16x8*)(a1);
  bf16x8 n0 = *(const bf16x8*)(a0 + 32);
  bf16x8 n1 = *(const bf16x8*)(a1 + 32);
  for (int k0 = 0; k0 < NENC; k0 += 64) {
    bf16x8 f0 = c0, f1 = c1;
    if (k0 + 64 < NENC) { c0 = *(const bf16x8*)(a0 + k0 + 64); c1 = *(const bf16x8*)(a1 + k0 + 64); }
#pragma unroll
    for (int nt = 0; nt < 4; ++nt) {
      bf16x8 bf = *(const bf16x8*)(b0 + (size_t)nt * 16 * NENC + k0);
      acc[0][nt] = MFMA16(f0, bf, acc[0][nt], 0, 0, 0);
      acc[1][nt] = MFMA16(f1, bf, acc[1][nt], 0, 0, 0);
    }
    bf16x8 g0 = n0, g1 = n1;
    if (k0 + 96 < NENC) { n0 = *(const bf16x8*)(a0 + k0 + 96); n1 = *(const bf16x8*)(a1 + k0 + 96); }
#pragma unroll
    for (int nt = 0; nt < 4; ++nt) {
      bf16x8 bf = *(const bf16x8*)(b0 + (size_t)nt * 16 * NENC + k0 + 32);
      acc[0][nt] = MFMA16(g0, bf, acc[0][nt], 0, 0, 0);
      acc[1][nt] = MFMA16(g1, bf, acc[1][nt], 0, 0, 0);
    }
  }
#pragma unroll
  for (int mt2 = 0; mt2 < 2; ++mt2)
#pragma unroll
    for (int nt = 0; nt < 4; ++nt)
#pragma unroll
      for (int j = 0; j < 4; ++j) {
        int row = mb + mt2 * 16 + lg * 4 + j;
        int col = nb + nt * 16 + lr;
        D[(size_t)row * NA + col] = f2b(acc[mt2][nt][j] + bias[col]);
      }
}

// ---------------- persistent loop: 256 blocks x 1024 threads ----------------
__global__ __launch_bounds__(1024) void kLoop(
    const u16* __restrict__ featsb, const u16* __restrict__ encb,
    const u16* __restrict__ WdgT, const u16* __restrict__ WifgoT2,
    const u16* __restrict__ embAll,
    const float* __restrict__ b_dec, const float* __restrict__ b_beta,
    const float* __restrict__ b_ih, const float* __restrict__ b_hh,
    const float* __restrict__ w_full, const float* __restrict__ b_full,
    const int* __restrict__ nact,
    float* __restrict__ cst, u16* __restrict__ hb,
    u16* xh0, u16* xh1, u16* __restrict__ hnewAll,
    float* __restrict__ dec_proj, float* __restrict__ gate_raw,
    float* __restrict__ out_alph, unsigned int* bar) {
  __shared__ float smem[8 * 32 * 33];          // 33.8 KB, unioned across phases
  float* s_dp = smem;                          // 512
  float* s_wf = smem + 512;                    // 512
  float* s_al = smem + 1024;                   // 256 (196 used)
  float* red  = smem + 1280;                   // 33

  int bid = blockIdx.x, tid = threadIdx.x;
  int w = tid >> 6, lane = tid & 63;
  int lr = lane & 15, lg = lane >> 4;
  int barK = 0;
  u16* xha = xh0;
  u16* xhb = xh1;
  float bf_ = b_full[0];

  for (int t = 0; t < NT; ++t) {
    int nact_t = nact[t];

    // ===== phase A: dec_proj & gate_raw = h @ WdgT (320 x 32x32 tiles) =====
    {
      int tile = w * 256 + bid;
      if (tile < 320) {
        int rt = tile & 3, ct = tile >> 2;
        int mb = rt * 32, nb = ct * 32;
        if (mb < nact_t) {
          f32x4 acc[2][2] = {};
          const u16* pa0 = hb + (size_t)(mb + lr) * ND + lg * 8;
          const u16* pa1 = pa0 + 16 * ND;
          const u16* pb0 = WdgT + (size_t)(nb + lr) * ND + lg * 8;
          const u16* pb1 = pb0 + 16 * ND;
#pragma unroll 4
          for (int k0 = 0; k0 < ND; k0 += 32) {
            bf16x8 af0 = *(const bf16x8*)(pa0 + k0);
            bf16x8 af1 = *(const bf16x8*)(pa1 + k0);
            bf16x8 bv0 = *(const bf16x8*)(pb0 + k0);
            bf16x8 bv1 = *(const bf16x8*)(pb1 + k0);
            acc[0][0] = MFMA16(af0, bv0, acc[0][0], 0, 0, 0);
            acc[1][0] = MFMA16(af1, bv0, acc[1][0], 0, 0, 0);
            acc[0][1] = MFMA16(af0, bv1, acc[0][1], 0, 0, 0);
            acc[1][1] = MFMA16(af1, bv1, acc[1][1], 0, 0, 0);
          }
#pragma unroll
          for (int m2 = 0; m2 < 2; ++m2)
#pragma unroll
            for (int n2 = 0; n2 < 2; ++n2)
#pragma unroll
              for (int j = 0; j < 4; ++j) {
                int row = mb + m2 * 16 + lg * 4 + j;
                int n = nb + n2 * 16 + lr;
                if (n < NA)
                  dec_proj[(size_t)row * NA + n] = acc[m2][n2][j] + b_dec[n];
                else
                  gate_raw[(size_t)row * NENC + (n - NA)] = acc[m2][n2][j] + b_beta[n - NA];
              }
        }
      }
    }
    gsync(bar, bid, barK++);

    // ===== phase B: scores + softmax + attw (2 blocks/batch, 1024 thr) =====
    {
      int b = bid >> 1, r = bid & 1;
      if (b < nact_t) {
        if (tid < NA) { s_dp[tid] = dec_proj[(size_t)b * NA + tid]; s_wf[tid] = w_full[tid]; }
        __syncthreads();
        for (int p = w; p < NP; p += 16) {
          const u16* ep = encb + ((size_t)b * NP + p) * NA + lane * 8;
          u16x8 v = *(const u16x8*)ep;
          float acc = 0.0f;
#pragma unroll
          for (int j = 0; j < 8; ++j) {
            int a = lane * 8 + j;
            float vv = b2f(v[j]) + s_dp[a];
            acc += fmaxf(vv, 0.0f) * s_wf[a];
          }
#pragma unroll
          for (int off = 32; off; off >>= 1) acc += __shfl_down(acc, off);
          if (lane == 0) s_al[p] = acc + bf_;
        }
        __syncthreads();
        float mx = (tid < NP) ? s_al[tid] : -3.4e38f;
#pragma unroll
        for (int off = 32; off; off >>= 1) mx = fmaxf(mx, __shfl_down(mx, off));
        if (lane == 0) red[w] = mx;
        __syncthreads();
        if (tid == 0) {
          float m = red[0];
          for (int i = 1; i < 16; ++i) m = fmaxf(m, red[i]);
          red[0] = m;
        }
        __syncthreads();
        float m2v = red[0];
        float e = 0.0f;
        if (tid < NP) { e = __expf(s_al[tid] - m2v); s_al[tid] = e; }
#pragma unroll
        for (int off = 32; off; off >>= 1) e += __shfl_down(e, off);
        if (lane == 0) red[16 + w] = e;
        __syncthreads();
        if (tid == 0) {
          float s = 0.0f;
          for (int i = 0; i < 16; ++i) s += red[16 + i];
          red[16] = 1.0f / s;
        }
        __syncthreads();
        float inv = red[16];
        if (tid < NP) {
          float al = s_al[tid] * inv;
          s_al[tid] = al;
          if (r == 0) out_alph[((size_t)b * NT + t) * NP + tid] = al;
        }
        __syncthreads();
        int e0 = r * 1024 + tid;
        float acw = 0.0f;
        const u16* fb = featsb + (size_t)b * NP * NENC + e0;
#pragma unroll 4
        for (int p = 0; p < NP; ++p) acw += s_al[p] * b2f(fb[(size_t)p * NENC]);
        float g = sigmoidf_(gate_raw[(size_t)b * NENC + e0]);
        xha[(size_t)b * KXH2 + e0] = f2b(acw * g);
      }
    }
    gsync(bar, bid, barK++);

    // ===== phase C: gates GEMM (32x32 tile/block, 8-way K-split) + LSTM =====
    {
      int rt = bid & 3, ct = bid >> 2;          // 4 x 64
      int mb = rt * 32, nb = ct * 32;
      int kq = w >> 1, mh = w & 1;              // 8 K-splits x 2 M-halves
      if (mb < nact_t) {
        f32x4 acc0 = {}, acc1 = {};
        const u16* pa = xha + (size_t)(mb + mh * 16 + lr) * KXH2 + kq * 320 + lg * 8;
        const u16* pb0 = WifgoT2 + (size_t)(nb + lr) * KXH2 + kq * 320 + lg * 8;
        const u16* pb1 = pb0 + (size_t)16 * KXH2;
#pragma unroll
        for (int k0 = 0; k0 < 320; k0 += 32) {
          bf16x8 af = *(const bf16x8*)(pa + k0);
          bf16x8 bv0 = *(const bf16x8*)(pb0 + k0);
          bf16x8 bv1 = *(const bf16x8*)(pb1 + k0);
          acc0 = MFMA16(af, bv0, acc0, 0, 0, 0);
          acc1 = MFMA16(af, bv1, acc1, 0, 0, 0);
        }
#pragma unroll
        for (int j = 0; j < 4; ++j) {
          int rr = kq * 32 + mh * 16 + lg * 4 + j;
          smem[rr * 33 + lr] = acc0[j];
          smem[rr * 33 + 16 + lr] = acc1[j];
        }
      }
      __syncthreads();
      if (tid < 256) {
        int row = tid >> 3, dl = tid & 7;
        int grow = mb + row;
        int d = ct * 8 + dl;
        size_t off = (size_t)grow * ND + d;
        if (grow < nact_t) {
          float g4[4];
#pragma unroll
          for (int g = 0; g < 4; ++g) {
            int col = dl * 4 + g;
            float s = 0.0f;
#pragma unroll
            for (int q = 0; q < 8; ++q) s += smem[(q * 32 + row) * 33 + col];
            s += b2f(embAll[((size_t)t * NB + grow) * NENC + nb + col]);
            g4[g] = s;
          }
          float gi = g4[0] + b_ih[d] + b_hh[d];
          float gf = g4[1] + b_ih[ND + d] + b_hh[ND + d];
          float gg = g4[2] + b_ih[2 * ND + d] + b_hh[2 * ND + d];
          float go = g4[3] + b_ih[3 * ND + d] + b_hh[3 * ND + d];
          float cn = sigmoidf_(gf) * cst[off] + sigmoidf_(gi) * tanhf(gg);
          float hn = sigmoidf_(go) * tanhf(cn);
          u16 hv = f2b(hn);
          cst[off] = cn;
          hb[off] = hv;
          hnewAll[(size_t)t * NB * ND + off] = hv;
          xhb[(size_t)grow * KXH2 + NENC + d] = hv;
        } else {
          xhb[(size_t)grow * KXH2 + NENC + d] = hb[off];
        }
      }
    }
    gsync(bar, bid, barK++);
    u16* tmp = xha; xha = xhb; xhb = tmp;
  }
}

// ---------------- batched preds GEMM (post-loop) ----------------
__global__ __launch_bounds__(256) void kPredsAll(const u16* __restrict__ hnewAll,
                                                 const u16* __restrict__ BT,
                                                 const float* __restrict__ b_fc,
                                                 const int* __restrict__ nact,
                                                 float* __restrict__ out_pred) {
  int t = blockIdx.y;
  int nact_t = nact[t];
  int w = threadIdx.x >> 6, lane = threadIdx.x & 63;
  int lr = lane & 15, lg = lane >> 4;
  int mb = w * 32;
  int nb = blockIdx.x * 64;
  f32x4 acc[2][4] = {};
  if (mb < nact_t) {
    const u16* a0 = hnewAll + (size_t)t * NB * ND + (size_t)(mb + lr) * ND + lg * 8;
    const u16* a1 = a0 + 16 * ND;
    const u16* b0 = BT + (size_t)(nb + lr) * ND + lg * 8;
    for (int k0 = 0; k0 < ND; k0 += 32) {
      bf16x8 af0 = *(const bf16x8*)(a0 + k0);
      bf16x8 af1 = *(const bf16x8*)(a1 + k0);
#pragma unroll
      for (int nt = 0; nt < 4; ++nt) {
        bf16x8 bf = *(const bf16x8*)(b0 + (size_t)nt * 16 * ND + k0);
        acc[0][nt] = MFMA16(af0, bf, acc[0][nt], 0, 0, 0);
        acc[1][nt] = MFMA16(af1, bf, acc[1][nt], 0, 0, 0);
      }
    }
  }
#pragma unroll
  for (int mt = 0; mt < 2; ++mt)
#pragma unroll
    for (int nt = 0; nt < 4; ++nt)
#pragma unroll
      for (int j = 0; j < 4; ++j) {
        int gn = nb + nt * 16 + lr;
        if (gn < NV) {
          int row = mb + mt * 16 + lg * 4 + j;
          float v = (row < nact_t) ? (acc[mt][nt][j] + b_fc[gn]) : 0.0f;
          __builtin_nontemporal_store(v, &out_pred[((size_t)row * NT + t) * NV + gn]);
        }
      }
}

extern "C" void kernel_launch(void* const* d_in, const int* in_sizes, int n_in,
                              void* d_out, int out_size, void* d_ws, size_t ws_size,
                              hipStream_t stream) {
  (void)in_sizes; (void)n_in; (void)out_size; (void)ws_size;
  const float* features  = (const float*)d_in[0];
  const int*   captions  = (const int*)d_in[1];
  const int*   cap_len   = (const int*)d_in[2];
  const float* emb       = (const float*)d_in[3];
  const float* W_enc_att = (const float*)d_in[4];
  const float* b_enc_att = (const float*)d_in[5];
  const float* W_dec_att = (const float*)d_in[6];
  const float* b_dec_att = (const float*)d_in[7];
  const float* w_full    = (const float*)d_in[8];
  const float* b_full    = (const float*)d_in[9];
  const float* W_h0      = (const float*)d_in[10];
  const float* b_h0      = (const float*)d_in[11];
  const float* W_c0      = (const float*)d_in[12];
  const float* b_c0      = (const float*)d_in[13];
  const float* W_beta    = (const float*)d_in[14];
  const float* b_beta    = (const float*)d_in[15];
  const float* W_ih      = (const float*)d_in[16];
  const float* b_ih      = (const float*)d_in[17];
  const float* W_hh      = (const float*)d_in[18];
  const float* b_hh      = (const float*)d_in[19];
  const float* W_fc      = (const float*)d_in[20];
  const float* b_fc      = (const float*)d_in[21];

  float* out      = (float*)d_out;
  float* out_pred = out;
  float* out_cap  = out_pred + (size_t)NB * NT * NV;
  float* out_dlen = out_cap + (size_t)NB * NL;
  float* out_alph = out_dlen + NB;

  char* p = (char*)d_ws;
  auto alloc = [&](size_t nbytes) { void* r = (void*)p; p += (nbytes + 255) & ~(size_t)255; return r; };
  int*   order    = (int*)alloc(NB * 4);
  int*   nact     = (int*)alloc(NT * 4);
  unsigned int* bar = (unsigned int*)alloc(1024);
  float* eo       = (float*)alloc((size_t)NB * NENC * 4);
  float* c        = (float*)alloc((size_t)NB * ND * 4);
  u16*   hb       = (u16*)alloc((size_t)NB * ND * 2);
  u16*   xh0      = (u16*)alloc((size_t)NB * KXH2 * 2);
  u16*   xh1      = (u16*)alloc((size_t)NB * KXH2 * 2);
  u16*   hnewAll  = (u16*)alloc((size_t)NT * NB * ND * 2);
  float* dec_proj = (float*)alloc((size_t)NB * NA * 4);
  float* gate_raw = (float*)alloc((size_t)NB * NENC * 4);
  u16*   featsb   = (u16*)alloc((size_t)NB * NP * NENC * 2);
  u16*   encb     = (u16*)alloc((size_t)NB * NP * NA * 2);
  u16*   WencT    = (u16*)alloc((size_t)NA * NENC * 2);
  u16*   WdgT     = (u16*)alloc((size_t)(NA + NENC) * ND * 2);
  u16*   WihTopT  = (u16*)alloc((size_t)NENC * NE * 2);
  u16*   WifgoT2  = (u16*)alloc((size_t)NENC * KXH2 * 2);
  u16*   WfcT     = (u16*)alloc((size_t)NVPAD * ND * 2);
  u16*   embA     = (u16*)alloc((size_t)NT * NB * NE * 2);
  u16*   embAll   = (u16*)alloc((size_t)NT * NB * NENC * 2);

  hipMemsetAsync(bar, 0, 1024, stream);
  kSort<<<1, NB, 0, stream>>>(cap_len, captions, order, nact, out_cap, out_dlen);
  kAlphaZero<<<NT, 256, 0, stream>>>(nact, out_alph);
  kFeats<<<dim3(NP, NB), 256, 0, stream>>>(features, order, featsb);
  kTWenc<<<NA, 256, 0, stream>>>(W_enc_att, WencT);
  kTdg<<<NA + NENC, 256, 0, stream>>>(W_dec_att, W_beta, WdgT);
  kTWihTop<<<NENC, 256, 0, stream>>>(W_ih, WihTopT);
  kTifgo2<<<NENC, 256, 0, stream>>>(W_ih, W_hh, WifgoT2);
  kTfc<<<NVPAD, 256, 0, stream>>>(W_fc, WfcT);
  kEmbA<<<dim3(NT, NB), 256, 0, stream>>>(emb, captions, order, embA);
  kEmbGemm<<<dim3(NENC / 64, NT), 256, 0, stream>>>(embA, WihTopT, embAll);
  kEo<<<dim3(NENC / 256, NB), 256, 0, stream>>>(featsb, eo);
  kInitHC<<<dim3(ND / 256, NB, 2), 256, 0, stream>>>(eo, W_h0, b_h0, W_c0, b_c0, hb, xh0, c);
  kEncProj<<<1600, 256, 0, stream>>>(featsb, WencT, b_enc_att, encb);

  kLoop<<<256, 1024, 0, stream>>>(featsb, encb, WdgT, WifgoT2, embAll,
                                  b_dec_att, b_beta, b_ih, b_hh, w_full, b_full,
                                  nact, c, hb, xh0, xh1, hnewAll,
                                  dec_proj, gate_raw, out_alph, bar);

  kPredsAll<<<dim3(NVPAD / 64, NT), 256, 0, stream>>>(hnewAll, WfcT, b_fc, nact, out_pred);
}

// Round 7
// 7352.573 us; speedup vs baseline: 1.0853x; 1.0853x over previous
//
#include <hip/hip_runtime.h>
#include <math.h>

#define NB 128
#define NP 196
#define NENC 2048
#define NE 512
#define ND 512
#define NA 512
#define NV 10000
#define NVPAD 10112
#define NL 52
#define NT 51
#define KXH2 2560   // [attw 2048 | h 512]

typedef unsigned short u16;
typedef __attribute__((ext_vector_type(8))) short bf16x8;
typedef __attribute__((ext_vector_type(8))) unsigned short u16x8;
typedef __attribute__((ext_vector_type(4))) float f32x4;

#define MFMA16 __builtin_amdgcn_mfma_f32_16x16x32_bf16

__device__ __forceinline__ float sigmoidf_(float v) { return 1.0f / (1.0f + __expf(-v)); }
__device__ __forceinline__ float b2f(u16 u) { return __uint_as_float(((unsigned int)u) << 16); }
__device__ __forceinline__ u16 f2b(float f) {
  unsigned int u = __float_as_uint(f);
  unsigned int r = (u + 0x7FFFu + ((u >> 16) & 1u)) >> 16;
  return (u16)r;
}

// ---------------- sort + nact ----------------
__global__ void kSort(const int* __restrict__ cap_len, const int* __restrict__ captions,
                      int* __restrict__ order, int* __restrict__ nact,
                      float* __restrict__ out_cap, float* __restrict__ out_dlen) {
  __shared__ int lens[NB];
  __shared__ int s_dl[NB];
  int tid = threadIdx.x;
  lens[tid] = cap_len[tid];
  __syncthreads();
  int li = lens[tid];
  int r = 0;
  for (int j = 0; j < NB; ++j) {
    int lj = lens[j];
    if (lj > li || (lj == li && j < tid)) r++;
  }
  order[r] = tid;
  s_dl[r] = li - 1;
  out_dlen[r] = (float)(li - 1);
  for (int l = 0; l < NL; ++l)
    out_cap[(size_t)r * NL + l] = (float)captions[(size_t)tid * NL + l];
  __syncthreads();
  if (tid < NT) {
    int cnt = 0;
    for (int j = 0; j < NB; ++j) cnt += (s_dl[j] > tid) ? 1 : 0;
    nact[tid] = cnt;
  }
}

__global__ void kAlphaZero(const int* __restrict__ nact, float* __restrict__ out_alph) {
  int t = blockIdx.x;
  int n0 = nact[t];
  int cnt = (NB - n0) * NP;
  for (int i = threadIdx.x; i < cnt; i += 256) {
    int b = n0 + i / NP;
    int p = i - (i / NP) * NP;
    out_alph[((size_t)b * NT + t) * NP + p] = 0.0f;
  }
}

// ---------------- features gather + bf16 ----------------
__global__ void kFeats(const float* __restrict__ features, const int* __restrict__ order,
                       u16* __restrict__ featsb) {
  int p = blockIdx.x, b = blockIdx.y, tid = threadIdx.x;
  const float* src = features + ((size_t)order[b] * NP + p) * NENC + tid * 8;
  u16* dst = featsb + ((size_t)b * NP + p) * NENC + tid * 8;
  float4 v0 = *(const float4*)src;
  float4 v1 = *(const float4*)(src + 4);
  u16x8 o;
  o[0] = f2b(v0.x); o[1] = f2b(v0.y); o[2] = f2b(v0.z); o[3] = f2b(v0.w);
  o[4] = f2b(v1.x); o[5] = f2b(v1.y); o[6] = f2b(v1.z); o[7] = f2b(v1.w);
  *(u16x8*)dst = o;
}

// ---------------- weight transposes ----------------
__global__ void kTWenc(const float* __restrict__ W, u16* __restrict__ dst) {
  int n = blockIdx.x;
  for (int k = threadIdx.x; k < NENC; k += 256)
    dst[(size_t)n * NENC + k] = f2b(W[(size_t)k * NA + n]);
}
__global__ void kTdg(const float* __restrict__ Wdec, const float* __restrict__ Wbeta,
                     u16* __restrict__ dst) {
  int n = blockIdx.x;  // 2560
  for (int k = threadIdx.x; k < ND; k += 256) {
    float v = (n < NA) ? Wdec[(size_t)k * NA + n] : Wbeta[(size_t)k * NENC + (n - NA)];
    dst[(size_t)n * ND + k] = f2b(v);
  }
}
__global__ void kTWihTop(const float* __restrict__ Wih, u16* __restrict__ dst) {
  int n = blockIdx.x;  // 2048, col interleaved n = d*4+g
  int col = (n & 3) * ND + (n >> 2);
  for (int k = threadIdx.x; k < NE; k += 256)
    dst[(size_t)n * NE + k] = f2b(Wih[(size_t)k * (4 * ND) + col]);
}
__global__ void kTifgo2(const float* __restrict__ Wih, const float* __restrict__ Whh,
                        u16* __restrict__ dst) {
  int n = blockIdx.x;  // 2048
  int col = (n & 3) * ND + (n >> 2);
  for (int k = threadIdx.x; k < KXH2; k += 256) {
    float v = (k < NENC) ? Wih[(size_t)(NE + k) * (4 * ND) + col]
                         : Whh[(size_t)(k - NENC) * (4 * ND) + col];
    dst[(size_t)n * KXH2 + k] = f2b(v);
  }
}
__global__ void kTfc(const float* __restrict__ Wfc, u16* __restrict__ dst) {
  int n = blockIdx.x;  // NVPAD
  for (int k = threadIdx.x; k < ND; k += 256) {
    float v = (n < NV) ? Wfc[(size_t)k * NV + n] : 0.0f;
    dst[(size_t)n * ND + k] = f2b(v);
  }
}

// ---------------- embA: gather caption embeddings (bf16) ----------------
__global__ void kEmbA(const float* __restrict__ emb, const int* __restrict__ captions,
                      const int* __restrict__ order, u16* __restrict__ embA) {
  int t = blockIdx.x, b = blockIdx.y;
  int tok = captions[(size_t)order[b] * NL + t];
  int i = threadIdx.x * 2;
  float2 v = *(const float2*)(emb + (size_t)tok * NE + i);
  unsigned int w0 = (unsigned int)f2b(v.x) | ((unsigned int)f2b(v.y) << 16);
  *(unsigned int*)(embA + ((size_t)t * NB + b) * NE + i) = w0;
}

// ---------------- embAll = embA @ WihTopT (bf16 out, K=512) ----------------
__global__ __launch_bounds__(256) void kEmbGemm(const u16* __restrict__ A,
                                                const u16* __restrict__ BT,
                                                u16* __restrict__ D) {
  int w = threadIdx.x >> 6, lane = threadIdx.x & 63;
  int lr = lane & 15, lg = lane >> 4;
  int mb = blockIdx.y * 128 + w * 32;
  int nb = blockIdx.x * 64;
  f32x4 acc[2][4] = {};
  const u16* a0 = A + (size_t)(mb + lr) * NE + lg * 8;
  const u16* a1 = a0 + 16 * NE;
  const u16* b0 = BT + (size_t)(nb + lr) * NE + lg * 8;
  for (int k0 = 0; k0 < NE; k0 += 32) {
    bf16x8 af0 = *(const bf16x8*)(a0 + k0);
    bf16x8 af1 = *(const bf16x8*)(a1 + k0);
#pragma unroll
    for (int nt = 0; nt < 4; ++nt) {
      bf16x8 bf = *(const bf16x8*)(b0 + (size_t)nt * 16 * NE + k0);
      acc[0][nt] = MFMA16(af0, bf, acc[0][nt], 0, 0, 0);
      acc[1][nt] = MFMA16(af1, bf, acc[1][nt], 0, 0, 0);
    }
  }
#pragma unroll
  for (int mt = 0; mt < 2; ++mt)
#pragma unroll
    for (int nt = 0; nt < 4; ++nt)
#pragma unroll
      for (int j = 0; j < 4; ++j) {
        int row = mb + mt * 16 + lg * 4 + j;
        int col = nb + nt * 16 + lr;
        D[(size_t)row * NENC + col] = f2b(acc[mt][nt][j]);
      }
}

// ---------------- eo = mean over P ----------------
__global__ void kEo(const u16* __restrict__ featsb, float* __restrict__ eo) {
  int e = blockIdx.x * 256 + threadIdx.x;
  int b = blockIdx.y;
  const u16* f = featsb + (size_t)b * NP * NENC + e;
  float s = 0.0f;
  for (int p = 0; p < NP; ++p) s += b2f(f[(size_t)p * NENC]);
  eo[(size_t)b * NENC + e] = s * (1.0f / NP);
}

// ---------------- h0 / c0 ----------------
__global__ void kInitHC(const float* __restrict__ eo,
                        const float* __restrict__ W_h0, const float* __restrict__ b_h0,
                        const float* __restrict__ W_c0, const float* __restrict__ b_c0,
                        u16* __restrict__ hb, u16* __restrict__ xh0, float* __restrict__ c) {
  __shared__ float s_eo[NENC];
  int b = blockIdx.y;
  for (int i = threadIdx.x; i < NENC; i += 256) s_eo[i] = eo[(size_t)b * NENC + i];
  __syncthreads();
  int d = blockIdx.x * 256 + threadIdx.x;
  const float* W = blockIdx.z ? W_c0 : W_h0;
  const float* bias = blockIdx.z ? b_c0 : b_h0;
  float acc = bias[d];
  for (int k = 0; k < NENC; ++k) acc += s_eo[k] * W[(size_t)k * ND + d];
  if (blockIdx.z) {
    c[(size_t)b * ND + d] = acc;
  } else {
    u16 hv = f2b(acc);
    hb[(size_t)b * ND + d] = hv;
    xh0[(size_t)b * KXH2 + NENC + d] = hv;
  }
}

// ---------------- enc_proj: LDS-staged A, reg prefetch, direct-B MFMA ----------------
// A [25088][2048] bf16, BT [512][2048], D [25088][512]. Tile 128x128, BK=64.
__global__ __launch_bounds__(256) void kEncProj(const u16* __restrict__ A,
                                                const u16* __restrict__ BT,
                                                const float* __restrict__ bias,
                                                u16* __restrict__ D) {
  __shared__ u16 As[128][72];   // padded: row stride 144B -> 2-way-free ds_read
  int bid = blockIdx.x;         // 784 = 196 Mtiles x 4 Ntiles
  int mt = bid >> 2, ntile = bid & 3;
  int mb = mt * 128, nb = ntile * 128;
  int tid = threadIdx.x;
  int w = tid >> 6, lane = tid & 63;
  int lr = lane & 15, lg = lane >> 4;

  // staging map: idx = i*256+tid -> row = idx>>3 (0..127), kp = idx&7 (16B chunk)
  int arow[4], akp[4];
  const u16* aptr[4];
#pragma unroll
  for (int i = 0; i < 4; ++i) {
    int idx = i * 256 + tid;
    arow[i] = idx >> 3;
    akp[i] = idx & 7;
    aptr[i] = A + (size_t)(mb + arow[i]) * NENC + akp[i] * 8;
  }
  u16x8 stg0, stg1, stg2, stg3;
  stg0 = *(const u16x8*)(aptr[0]);
  stg1 = *(const u16x8*)(aptr[1]);
  stg2 = *(const u16x8*)(aptr[2]);
  stg3 = *(const u16x8*)(aptr[3]);

  f32x4 acc[2][8] = {};
  const u16* bbase = BT + (size_t)(nb + lr) * NENC + lg * 8;

  for (int k0 = 0; k0 < NENC; k0 += 64) {
    __syncthreads();  // previous compute finished reading As
    *(u16x8*)&As[arow[0]][akp[0] * 8] = stg0;
    *(u16x8*)&As[arow[1]][akp[1] * 8] = stg1;
    *(u16x8*)&As[arow[2]][akp[2] * 8] = stg2;
    *(u16x8*)&As[arow[3]][akp[3] * 8] = stg3;
    if (k0 + 64 < NENC) {
      stg0 = *(const u16x8*)(aptr[0] + k0 + 64);
      stg1 = *(const u16x8*)(aptr[1] + k0 + 64);
      stg2 = *(const u16x8*)(aptr[2] + k0 + 64);
      stg3 = *(const u16x8*)(aptr[3] + k0 + 64);
    }
    __syncthreads();
#pragma unroll
    for (int kh = 0; kh < 2; ++kh) {
      int r0 = w * 32 + lr;
      bf16x8 af0 = *(const bf16x8*)&As[r0][kh * 32 + lg * 8];
      bf16x8 af1 = *(const bf16x8*)&As[r0 + 16][kh * 32 + lg * 8];
#pragma unroll
      for (int nt = 0; nt < 8; ++nt) {
        bf16x8 bf = *(const bf16x8*)(bbase + (size_t)nt * 16 * NENC + k0 + kh * 32);
        acc[0][nt] = MFMA16(af0, bf, acc[0][nt], 0, 0, 0);
        acc[1][nt] = MFMA16(af1, bf, acc[1][nt], 0, 0, 0);
      }
    }
  }
#pragma unroll
  for (int m2 = 0; m2 < 2; ++m2)
#pragma unroll
    for (int nt = 0; nt < 8; ++nt)
#pragma unroll
      for (int j = 0; j < 4; ++j) {
        int row = mb + w * 32 + m2 * 16 + lg * 4 + j;
        int col = nb + nt * 16 + lr;
        D[(size_t)row * NA + col] = f2b(acc[m2][nt][j] + bias[col]);
      }
}

// ---------------- kStep1: dec_proj + scores + softmax + gate + attw + x (fused) ----------------
// grid (NB, 4), 256 threads. Slice r handles attw/gate cols [r*512, r*512+512).
__global__ __launch_bounds__(256) void kStep1(const u16* __restrict__ featsb,
                                              const u16* __restrict__ encb,
                                              const u16* __restrict__ WdgT,  // [2560][512]
                                              const u16* __restrict__ hb,
                                              const float* __restrict__ w_full,
                                              const float* __restrict__ b_full,
                                              const float* __restrict__ b_dec,
                                              const float* __restrict__ b_beta,
                                              const int* __restrict__ nact, int t,
                                              u16* __restrict__ xh_w,
                                              float* __restrict__ out_alph) {
  int b = blockIdx.x, r = blockIdx.y, tid = threadIdx.x;
  if (b >= nact[t]) return;
  __shared__ float s_h[ND];
  __shared__ float s_dp[NA];
  __shared__ float s_wf[NA];
  __shared__ float s_al[NP + 12];
  __shared__ float red[16];
  int wave = tid >> 6, lane = tid & 63;

  s_h[tid] = b2f(hb[(size_t)b * ND + tid]);
  s_h[tid + 256] = b2f(hb[(size_t)b * ND + tid + 256]);
  s_wf[tid] = w_full[tid];
  s_wf[tid + 256] = w_full[tid + 256];
  __syncthreads();

  // dec_proj: 2 cols per thread (n = tid, tid+256)
#pragma unroll
  for (int cc = 0; cc < 2; ++cc) {
    int n = cc * 256 + tid;
    const u16* wr = WdgT + (size_t)n * ND;
    float acc = b_dec[n];
#pragma unroll 4
    for (int k0 = 0; k0 < ND; k0 += 8) {
      u16x8 wv = *(const u16x8*)(wr + k0);
#pragma unroll
      for (int j = 0; j < 8; ++j) acc += s_h[k0 + j] * b2f(wv[j]);
    }
    s_dp[n] = acc;
  }
  __syncthreads();

  // scores
  float bf_ = b_full[0];
  for (int p = wave; p < NP; p += 4) {
    const u16* ep = encb + ((size_t)b * NP + p) * NA + lane * 8;
    u16x8 v = *(const u16x8*)ep;
    float acc = 0.0f;
#pragma unroll
    for (int j = 0; j < 8; ++j) {
      int a = lane * 8 + j;
      float vv = b2f(v[j]) + s_dp[a];
      acc += fmaxf(vv, 0.0f) * s_wf[a];
    }
#pragma unroll
    for (int off = 32; off; off >>= 1) acc += __shfl_down(acc, off);
    if (lane == 0) s_al[p] = acc + bf_;
  }
  __syncthreads();
  float mx = -3.4e38f;
  for (int p = tid; p < NP; p += 256) mx = fmaxf(mx, s_al[p]);
#pragma unroll
  for (int off = 32; off; off >>= 1) mx = fmaxf(mx, __shfl_down(mx, off));
  if (lane == 0) red[wave] = mx;
  __syncthreads();
  if (tid == 0) red[0] = fmaxf(fmaxf(red[0], red[1]), fmaxf(red[2], red[3]));
  __syncthreads();
  float m2v = red[0];
  float sm = 0.0f;
  for (int p = tid; p < NP; p += 256) { float e = __expf(s_al[p] - m2v); s_al[p] = e; sm += e; }
#pragma unroll
  for (int off = 32; off; off >>= 1) sm += __shfl_down(sm, off);
  if (lane == 0) red[8 + wave] = sm;
  __syncthreads();
  if (tid == 0) red[8] = 1.0f / (red[8] + red[9] + red[10] + red[11]);
  __syncthreads();
  float inv = red[8];
  for (int p = tid; p < NP; p += 256) {
    float al = s_al[p] * inv;
    s_al[p] = al;
    if (r == 0) out_alph[((size_t)b * NT + t) * NP + p] = al;
  }
  __syncthreads();

  // gate + attw for 2 cols: e0 = r*512 + tid*2
  int e0 = r * 512 + tid * 2;
  float g0 = b_beta[e0], g1 = b_beta[e0 + 1];
  const u16* wb0 = WdgT + (size_t)(NA + e0) * ND;
  const u16* wb1 = wb0 + ND;
#pragma unroll 4
  for (int k0 = 0; k0 < ND; k0 += 8) {
    u16x8 w0 = *(const u16x8*)(wb0 + k0);
    u16x8 w1 = *(const u16x8*)(wb1 + k0);
#pragma unroll
    for (int j = 0; j < 8; ++j) {
      float hk = s_h[k0 + j];
      g0 += hk * b2f(w0[j]);
      g1 += hk * b2f(w1[j]);
    }
  }
  float ac0 = 0.0f, ac1 = 0.0f;
  const u16* fb = featsb + (size_t)b * NP * NENC + e0;
#pragma unroll 4
  for (int p = 0; p < NP; ++p) {
    unsigned int v = *(const unsigned int*)(fb + (size_t)p * NENC);
    float al = s_al[p];
    ac0 += al * __uint_as_float(v << 16);
    ac1 += al * __uint_as_float(v & 0xffff0000u);
  }
  unsigned int wo = (unsigned int)f2b(ac0 * sigmoidf_(g0)) |
                    ((unsigned int)f2b(ac1 * sigmoidf_(g1)) << 16);
  *(unsigned int*)(xh_w + (size_t)b * KXH2 + e0) = wo;
}

// ---------------- kGatesLstm: 32x32 tile/block, 8-way K-split + LSTM epilogue ----------------
__global__ __launch_bounds__(1024) void kGatesLstm(const u16* __restrict__ xh_r,
                                                   const u16* __restrict__ WifgoT2, // [2048][2560]
                                                   const u16* __restrict__ embAll,
                                                   const float* __restrict__ b_ih,
                                                   const float* __restrict__ b_hh,
                                                   const int* __restrict__ nact, int t,
                                                   float* __restrict__ cst,
                                                   u16* __restrict__ hb,
                                                   u16* __restrict__ hnewAll_t,
                                                   u16* __restrict__ xh_w) {
  __shared__ float smem[8 * 32 * 33];
  int nact_t = nact[t];
  int tid = threadIdx.x;
  int w = tid >> 6, lane = tid & 63;
  int lr = lane & 15, lg = lane >> 4;
  int rt = blockIdx.x & 3, ct = blockIdx.x >> 2;   // 4 Mtiles x 64 Ntiles
  int mb = rt * 32, nb = ct * 32;
  int kq = w >> 1, mh = w & 1;                     // 8 K-splits x 2 M-halves
  if (mb < nact_t) {
    f32x4 acc0 = {}, acc1 = {};
    const u16* pa = xh_r + (size_t)(mb + mh * 16 + lr) * KXH2 + kq * 320 + lg * 8;
    const u16* pb0 = WifgoT2 + (size_t)(nb + lr) * KXH2 + kq * 320 + lg * 8;
    const u16* pb1 = pb0 + (size_t)16 * KXH2;
#pragma unroll
    for (int k0 = 0; k0 < 320; k0 += 32) {
      bf16x8 af = *(const bf16x8*)(pa + k0);
      bf16x8 bv0 = *(const bf16x8*)(pb0 + k0);
      bf16x8 bv1 = *(const bf16x8*)(pb1 + k0);
      acc0 = MFMA16(af, bv0, acc0, 0, 0, 0);
      acc1 = MFMA16(af, bv1, acc1, 0, 0, 0);
    }
#pragma unroll
    for (int j = 0; j < 4; ++j) {
      int rr = kq * 32 + mh * 16 + lg * 4 + j;
      smem[rr * 33 + lr] = acc0[j];
      smem[rr * 33 + 16 + lr] = acc1[j];
    }
  }
  __syncthreads();
  if (tid < 256) {
    int row = tid >> 3, dl = tid & 7;
    int grow = mb + row;
    int d = ct * 8 + dl;
    size_t off = (size_t)grow * ND + d;
    if (grow < nact_t) {
      float g4[4];
#pragma unroll
      for (int g = 0; g < 4; ++g) {
        int col = dl * 4 + g;
        float s = 0.0f;
#pragma unroll
        for (int q = 0; q < 8; ++q) s += smem[(q * 32 + row) * 33 + col];
        s += b2f(embAll[((size_t)t * NB + grow) * NENC + nb + col]);
        g4[g] = s;
      }
      float gi = g4[0] + b_ih[d] + b_hh[d];
      float gf = g4[1] + b_ih[ND + d] + b_hh[ND + d];
      float gg = g4[2] + b_ih[2 * ND + d] + b_hh[2 * ND + d];
      float go = g4[3] + b_ih[3 * ND + d] + b_hh[3 * ND + d];
      float cn = sigmoidf_(gf) * cst[off] + sigmoidf_(gi) * tanhf(gg);
      float hn = sigmoidf_(go) * tanhf(cn);
      u16 hv = f2b(hn);
      cst[off] = cn;
      hb[off] = hv;
      hnewAll_t[off] = hv;
      xh_w[(size_t)grow * KXH2 + NENC + d] = hv;
    } else {
      xh_w[(size_t)grow * KXH2 + NENC + d] = hb[off];
    }
  }
}

// ---------------- batched preds GEMM (post-loop) ----------------
__global__ __launch_bounds__(256) void kPredsAll(const u16* __restrict__ hnewAll,
                                                 const u16* __restrict__ BT,
                                                 const float* __restrict__ b_fc,
                                                 const int* __restrict__ nact,
                                                 float* __restrict__ out_pred) {
  int t = blockIdx.y;
  int nact_t = nact[t];
  int w = threadIdx.x >> 6, lane = threadIdx.x & 63;
  int lr = lane & 15, lg = lane >> 4;
  int mb = w * 32;
  int nb = blockIdx.x * 64;
  f32x4 acc[2][4] = {};
  if (mb < nact_t) {
    const u16* a0 = hnewAll + (size_t)t * NB * ND + (size_t)(mb + lr) * ND + lg * 8;
    const u16* a1 = a0 + 16 * ND;
    const u16* b0 = BT + (size_t)(nb + lr) * ND + lg * 8;
    for (int k0 = 0; k0 < ND; k0 += 32) {
      bf16x8 af0 = *(const bf16x8*)(a0 + k0);
      bf16x8 af1 = *(const bf16x8*)(a1 + k0);
#pragma unroll
      for (int nt = 0; nt < 4; ++nt) {
        bf16x8 bf = *(const bf16x8*)(b0 + (size_t)nt * 16 * ND + k0);
        acc[0][nt] = MFMA16(af0, bf, acc[0][nt], 0, 0, 0);
        acc[1][nt] = MFMA16(af1, bf, acc[1][nt], 0, 0, 0);
      }
    }
  }
#pragma unroll
  for (int mt = 0; mt < 2; ++mt)
#pragma unroll
    for (int nt = 0; nt < 4; ++nt)
#pragma unroll
      for (int j = 0; j < 4; ++j) {
        int gn = nb + nt * 16 + lr;
        if (gn < NV) {
          int row = mb + mt * 16 + lg * 4 + j;
          float v = (row < nact_t) ? (acc[mt][nt][j] + b_fc[gn]) : 0.0f;
          __builtin_nontemporal_store(v, &out_pred[((size_t)row * NT + t) * NV + gn]);
        }
      }
}

extern "C" void kernel_launch(void* const* d_in, const int* in_sizes, int n_in,
                              void* d_out, int out_size, void* d_ws, size_t ws_size,
                              hipStream_t stream) {
  (void)in_sizes; (void)n_in; (void)out_size; (void)ws_size;
  const float* features  = (const float*)d_in[0];
  const int*   captions  = (const int*)d_in[1];
  const int*   cap_len   = (const int*)d_in[2];
  const float* emb       = (const float*)d_in[3];
  const float* W_enc_att = (const float*)d_in[4];
  const float* b_enc_att = (const float*)d_in[5];
  const float* W_dec_att = (const float*)d_in[6];
  const float* b_dec_att = (const float*)d_in[7];
  const float* w_full    = (const float*)d_in[8];
  const float* b_full    = (const float*)d_in[9];
  const float* W_h0      = (const float*)d_in[10];
  const float* b_h0      = (const float*)d_in[11];
  const float* W_c0      = (const float*)d_in[12];
  const float* b_c0      = (const float*)d_in[13];
  const float* W_beta    = (const float*)d_in[14];
  const float* b_beta    = (const float*)d_in[15];
  const float* W_ih      = (const float*)d_in[16];
  const float* b_ih      = (const float*)d_in[17];
  const float* W_hh      = (const float*)d_in[18];
  const float* b_hh      = (const float*)d_in[19];
  const float* W_fc      = (const float*)d_in[20];
  const float* b_fc      = (const float*)d_in[21];

  float* out      = (float*)d_out;
  float* out_pred = out;
  float* out_cap  = out_pred + (size_t)NB * NT * NV;
  float* out_dlen = out_cap + (size_t)NB * NL;
  float* out_alph = out_dlen + NB;

  char* p = (char*)d_ws;
  auto alloc = [&](size_t nbytes) { void* r = (void*)p; p += (nbytes + 255) & ~(size_t)255; return r; };
  int*   order    = (int*)alloc(NB * 4);
  int*   nact     = (int*)alloc(NT * 4);
  float* eo       = (float*)alloc((size_t)NB * NENC * 4);
  float* c        = (float*)alloc((size_t)NB * ND * 4);
  u16*   hb       = (u16*)alloc((size_t)NB * ND * 2);
  u16*   xh0      = (u16*)alloc((size_t)NB * KXH2 * 2);
  u16*   xh1      = (u16*)alloc((size_t)NB * KXH2 * 2);
  u16*   hnewAll  = (u16*)alloc((size_t)NT * NB * ND * 2);
  u16*   featsb   = (u16*)alloc((size_t)NB * NP * NENC * 2);
  u16*   encb     = (u16*)alloc((size_t)NB * NP * NA * 2);
  u16*   WencT    = (u16*)alloc((size_t)NA * NENC * 2);
  u16*   WdgT     = (u16*)alloc((size_t)(NA + NENC) * ND * 2);
  u16*   WihTopT  = (u16*)alloc((size_t)NENC * NE * 2);
  u16*   WifgoT2  = (u16*)alloc((size_t)NENC * KXH2 * 2);
  u16*   WfcT     = (u16*)alloc((size_t)NVPAD * ND * 2);
  u16*   embA     = (u16*)alloc((size_t)NT * NB * NE * 2);
  u16*   embAll   = (u16*)alloc((size_t)NT * NB * NENC * 2);

  kSort<<<1, NB, 0, stream>>>(cap_len, captions, order, nact, out_cap, out_dlen);
  kAlphaZero<<<NT, 256, 0, stream>>>(nact, out_alph);
  kFeats<<<dim3(NP, NB), 256, 0, stream>>>(features, order, featsb);
  kTWenc<<<NA, 256, 0, stream>>>(W_enc_att, WencT);
  kTdg<<<NA + NENC, 256, 0, stream>>>(W_dec_att, W_beta, WdgT);
  kTWihTop<<<NENC, 256, 0, stream>>>(W_ih, WihTopT);
  kTifgo2<<<NENC, 256, 0, stream>>>(W_ih, W_hh, WifgoT2);
  kTfc<<<NVPAD, 256, 0, stream>>>(W_fc, WfcT);
  kEmbA<<<dim3(NT, NB), 256, 0, stream>>>(emb, captions, order, embA);
  kEmbGemm<<<dim3(NENC / 64, NT), 256, 0, stream>>>(embA, WihTopT, embAll);
  kEo<<<dim3(NENC / 256, NB), 256, 0, stream>>>(featsb, eo);
  kInitHC<<<dim3(ND / 256, NB, 2), 256, 0, stream>>>(eo, W_h0, b_h0, W_c0, b_c0, hb, xh0, c);
  kEncProj<<<784, 256, 0, stream>>>(featsb, WencT, b_enc_att, encb);

  for (int t = 0; t < NT; ++t) {
    u16* xh_r = (t & 1) ? xh1 : xh0;
    u16* xh_w = (t & 1) ? xh0 : xh1;
    kStep1<<<dim3(NB, 4), 256, 0, stream>>>(featsb, encb, WdgT, hb, w_full, b_full,
                                            b_dec_att, b_beta, nact, t, xh_r, out_alph);
    kGatesLstm<<<256, 1024, 0, stream>>>(xh_r, WifgoT2, embAll, b_ih, b_hh, nact, t,
                                         c, hb, hnewAll + (size_t)t * NB * ND, xh_w);
  }
  kPredsAll<<<dim3(NVPAD / 64, NT), 256, 0, stream>>>(hnewAll, WfcT, b_fc, nact, out_pred);
}

// Round 8
// 4618.258 us; speedup vs baseline: 1.7279x; 1.5921x over previous
//
#include <hip/hip_runtime.h>
#include <math.h>

#define NB 128
#define NP 196
#define NENC 2048
#define NE 512
#define ND 512
#define NA 512
#define NV 10000
#define NVPAD 10112
#define NL 52
#define NT 51
#define KXH2 2560   // [attw 2048 | h 512]

typedef unsigned short u16;
typedef __attribute__((ext_vector_type(8))) short bf16x8;
typedef __attribute__((ext_vector_type(8))) unsigned short u16x8;
typedef __attribute__((ext_vector_type(4))) float f32x4;

#define MFMA16 __builtin_amdgcn_mfma_f32_16x16x32_bf16

__device__ __forceinline__ float sigmoidf_(float v) { return 1.0f / (1.0f + __expf(-v)); }
__device__ __forceinline__ float b2f(u16 u) { return __uint_as_float(((unsigned int)u) << 16); }
__device__ __forceinline__ u16 f2b(float f) {
  unsigned int u = __float_as_uint(f);
  unsigned int r = (u + 0x7FFFu + ((u >> 16) & 1u)) >> 16;
  return (u16)r;
}

// ---------------- sort + nact ----------------
__global__ void kSort(const int* __restrict__ cap_len, const int* __restrict__ captions,
                      int* __restrict__ order, int* __restrict__ nact,
                      float* __restrict__ out_cap, float* __restrict__ out_dlen) {
  __shared__ int lens[NB];
  __shared__ int s_dl[NB];
  int tid = threadIdx.x;
  lens[tid] = cap_len[tid];
  __syncthreads();
  int li = lens[tid];
  int r = 0;
  for (int j = 0; j < NB; ++j) {
    int lj = lens[j];
    if (lj > li || (lj == li && j < tid)) r++;
  }
  order[r] = tid;
  s_dl[r] = li - 1;
  out_dlen[r] = (float)(li - 1);
  for (int l = 0; l < NL; ++l)
    out_cap[(size_t)r * NL + l] = (float)captions[(size_t)tid * NL + l];
  __syncthreads();
  if (tid < NT) {
    int cnt = 0;
    for (int j = 0; j < NB; ++j) cnt += (s_dl[j] > tid) ? 1 : 0;
    nact[tid] = cnt;
  }
}

__global__ void kAlphaZero(const int* __restrict__ nact, float* __restrict__ out_alph) {
  int t = blockIdx.x;
  int n0 = nact[t];
  int cnt = (NB - n0) * NP;
  for (int i = threadIdx.x; i < cnt; i += 256) {
    int b = n0 + i / NP;
    int p = i - (i / NP) * NP;
    out_alph[((size_t)b * NT + t) * NP + p] = 0.0f;
  }
}

// ---------------- features gather + bf16 ----------------
__global__ void kFeats(const float* __restrict__ features, const int* __restrict__ order,
                       u16* __restrict__ featsb) {
  int p = blockIdx.x, b = blockIdx.y, tid = threadIdx.x;
  const float* src = features + ((size_t)order[b] * NP + p) * NENC + tid * 8;
  u16* dst = featsb + ((size_t)b * NP + p) * NENC + tid * 8;
  float4 v0 = *(const float4*)src;
  float4 v1 = *(const float4*)(src + 4);
  u16x8 o;
  o[0] = f2b(v0.x); o[1] = f2b(v0.y); o[2] = f2b(v0.z); o[3] = f2b(v0.w);
  o[4] = f2b(v1.x); o[5] = f2b(v1.y); o[6] = f2b(v1.z); o[7] = f2b(v1.w);
  *(u16x8*)dst = o;
}

// ---------------- weight transposes ----------------
__global__ void kTWenc(const float* __restrict__ W, u16* __restrict__ dst) {
  int n = blockIdx.x;
  for (int k = threadIdx.x; k < NENC; k += 256)
    dst[(size_t)n * NENC + k] = f2b(W[(size_t)k * NA + n]);
}
__global__ void kTdg(const float* __restrict__ Wdec, const float* __restrict__ Wbeta,
                     u16* __restrict__ dst) {
  int n = blockIdx.x;  // 2560
  for (int k = threadIdx.x; k < ND; k += 256) {
    float v = (n < NA) ? Wdec[(size_t)k * NA + n] : Wbeta[(size_t)k * NENC + (n - NA)];
    dst[(size_t)n * ND + k] = f2b(v);
  }
}
__global__ void kTWihTop(const float* __restrict__ Wih, u16* __restrict__ dst) {
  int n = blockIdx.x;  // 2048, col interleaved n = d*4+g
  int col = (n & 3) * ND + (n >> 2);
  for (int k = threadIdx.x; k < NE; k += 256)
    dst[(size_t)n * NE + k] = f2b(Wih[(size_t)k * (4 * ND) + col]);
}
__global__ void kTifgo2(const float* __restrict__ Wih, const float* __restrict__ Whh,
                        u16* __restrict__ dst) {
  int n = blockIdx.x;  // 2048
  int col = (n & 3) * ND + (n >> 2);
  for (int k = threadIdx.x; k < KXH2; k += 256) {
    float v = (k < NENC) ? Wih[(size_t)(NE + k) * (4 * ND) + col]
                         : Whh[(size_t)(k - NENC) * (4 * ND) + col];
    dst[(size_t)n * KXH2 + k] = f2b(v);
  }
}
__global__ void kTfc(const float* __restrict__ Wfc, u16* __restrict__ dst) {
  int n = blockIdx.x;  // NVPAD
  for (int k = threadIdx.x; k < ND; k += 256) {
    float v = (n < NV) ? Wfc[(size_t)k * NV + n] : 0.0f;
    dst[(size_t)n * ND + k] = f2b(v);
  }
}

// ---------------- embA: gather caption embeddings (bf16) ----------------
__global__ void kEmbA(const float* __restrict__ emb, const int* __restrict__ captions,
                      const int* __restrict__ order, u16* __restrict__ embA) {
  int t = blockIdx.x, b = blockIdx.y;
  int tok = captions[(size_t)order[b] * NL + t];
  int i = threadIdx.x * 2;
  float2 v = *(const float2*)(emb + (size_t)tok * NE + i);
  unsigned int w0 = (unsigned int)f2b(v.x) | ((unsigned int)f2b(v.y) << 16);
  *(unsigned int*)(embA + ((size_t)t * NB + b) * NE + i) = w0;
}

// ---------------- embAll = embA @ WihTopT (bf16 out, K=512) ----------------
__global__ __launch_bounds__(256) void kEmbGemm(const u16* __restrict__ A,
                                                const u16* __restrict__ BT,
                                                u16* __restrict__ D) {
  int w = threadIdx.x >> 6, lane = threadIdx.x & 63;
  int lr = lane & 15, lg = lane >> 4;
  int mb = blockIdx.y * 128 + w * 32;
  int nb = blockIdx.x * 64;
  f32x4 acc[2][4] = {};
  const u16* a0 = A + (size_t)(mb + lr) * NE + lg * 8;
  const u16* a1 = a0 + 16 * NE;
  const u16* b0 = BT + (size_t)(nb + lr) * NE + lg * 8;
  for (int k0 = 0; k0 < NE; k0 += 32) {
    bf16x8 af0 = *(const bf16x8*)(a0 + k0);
    bf16x8 af1 = *(const bf16x8*)(a1 + k0);
#pragma unroll
    for (int nt = 0; nt < 4; ++nt) {
      bf16x8 bf = *(const bf16x8*)(b0 + (size_t)nt * 16 * NE + k0);
      acc[0][nt] = MFMA16(af0, bf, acc[0][nt], 0, 0, 0);
      acc[1][nt] = MFMA16(af1, bf, acc[1][nt], 0, 0, 0);
    }
  }
#pragma unroll
  for (int mt = 0; mt < 2; ++mt)
#pragma unroll
    for (int nt = 0; nt < 4; ++nt)
#pragma unroll
      for (int j = 0; j < 4; ++j) {
        int row = mb + mt * 16 + lg * 4 + j;
        int col = nb + nt * 16 + lr;
        D[(size_t)row * NENC + col] = f2b(acc[mt][nt][j]);
      }
}

// ---------------- eo = mean over P ----------------
__global__ void kEo(const u16* __restrict__ featsb, float* __restrict__ eo) {
  int e = blockIdx.x * 256 + threadIdx.x;
  int b = blockIdx.y;
  const u16* f = featsb + (size_t)b * NP * NENC + e;
  float s = 0.0f;
  for (int p = 0; p < NP; ++p) s += b2f(f[(size_t)p * NENC]);
  eo[(size_t)b * NENC + e] = s * (1.0f / NP);
}

// ---------------- h0 / c0 ----------------
__global__ void kInitHC(const float* __restrict__ eo,
                        const float* __restrict__ W_h0, const float* __restrict__ b_h0,
                        const float* __restrict__ W_c0, const float* __restrict__ b_c0,
                        u16* __restrict__ hb, u16* __restrict__ xh0, float* __restrict__ c) {
  __shared__ float s_eo[NENC];
  int b = blockIdx.y;
  for (int i = threadIdx.x; i < NENC; i += 256) s_eo[i] = eo[(size_t)b * NENC + i];
  __syncthreads();
  int d = blockIdx.x * 256 + threadIdx.x;
  const float* W = blockIdx.z ? W_c0 : W_h0;
  const float* bias = blockIdx.z ? b_c0 : b_h0;
  float acc = bias[d];
  for (int k = 0; k < NENC; ++k) acc += s_eo[k] * W[(size_t)k * ND + d];
  if (blockIdx.z) {
    c[(size_t)b * ND + d] = acc;
  } else {
    u16 hv = f2b(acc);
    hb[(size_t)b * ND + d] = hv;
    xh0[(size_t)b * KXH2 + NENC + d] = hv;
  }
}

// ---------------- enc_proj: LDS-staged A, reg prefetch, direct-B MFMA ----------------
__global__ __launch_bounds__(256) void kEncProj(const u16* __restrict__ A,
                                                const u16* __restrict__ BT,
                                                const float* __restrict__ bias,
                                                u16* __restrict__ D) {
  __shared__ u16 As[128][72];
  int bid = blockIdx.x;         // 784 = 196 Mtiles x 4 Ntiles
  int mt = bid >> 2, ntile = bid & 3;
  int mb = mt * 128, nb = ntile * 128;
  int tid = threadIdx.x;
  int w = tid >> 6, lane = tid & 63;
  int lr = lane & 15, lg = lane >> 4;

  int arow[4], akp[4];
  const u16* aptr[4];
#pragma unroll
  for (int i = 0; i < 4; ++i) {
    int idx = i * 256 + tid;
    arow[i] = idx >> 3;
    akp[i] = idx & 7;
    aptr[i] = A + (size_t)(mb + arow[i]) * NENC + akp[i] * 8;
  }
  u16x8 stg0, stg1, stg2, stg3;
  stg0 = *(const u16x8*)(aptr[0]);
  stg1 = *(const u16x8*)(aptr[1]);
  stg2 = *(const u16x8*)(aptr[2]);
  stg3 = *(const u16x8*)(aptr[3]);

  f32x4 acc[2][8] = {};
  const u16* bbase = BT + (size_t)(nb + lr) * NENC + lg * 8;

  for (int k0 = 0; k0 < NENC; k0 += 64) {
    __syncthreads();
    *(u16x8*)&As[arow[0]][akp[0] * 8] = stg0;
    *(u16x8*)&As[arow[1]][akp[1] * 8] = stg1;
    *(u16x8*)&As[arow[2]][akp[2] * 8] = stg2;
    *(u16x8*)&As[arow[3]][akp[3] * 8] = stg3;
    if (k0 + 64 < NENC) {
      stg0 = *(const u16x8*)(aptr[0] + k0 + 64);
      stg1 = *(const u16x8*)(aptr[1] + k0 + 64);
      stg2 = *(const u16x8*)(aptr[2] + k0 + 64);
      stg3 = *(const u16x8*)(aptr[3] + k0 + 64);
    }
    __syncthreads();
#pragma unroll
    for (int kh = 0; kh < 2; ++kh) {
      int r0 = w * 32 + lr;
      bf16x8 af0 = *(const bf16x8*)&As[r0][kh * 32 + lg * 8];
      bf16x8 af1 = *(const bf16x8*)&As[r0 + 16][kh * 32 + lg * 8];
#pragma unroll
      for (int nt = 0; nt < 8; ++nt) {
        bf16x8 bf = *(const bf16x8*)(bbase + (size_t)nt * 16 * NENC + k0 + kh * 32);
        acc[0][nt] = MFMA16(af0, bf, acc[0][nt], 0, 0, 0);
        acc[1][nt] = MFMA16(af1, bf, acc[1][nt], 0, 0, 0);
      }
    }
  }
#pragma unroll
  for (int m2 = 0; m2 < 2; ++m2)
#pragma unroll
    for (int nt = 0; nt < 8; ++nt)
#pragma unroll
      for (int j = 0; j < 4; ++j) {
        int row = mb + w * 32 + m2 * 16 + lg * 4 + j;
        int col = nb + nt * 16 + lr;
        D[(size_t)row * NA + col] = f2b(acc[m2][nt][j] + bias[col]);
      }
}

// ---------------- kDecGate: dec_proj & gate_raw (MFMA, 32x32, 1-wave blocks) ----------------
__global__ __launch_bounds__(64) void kDecGate(const u16* __restrict__ hb,
                                               const u16* __restrict__ BT,   // [2560][512]
                                               const float* __restrict__ b_dec,
                                               const float* __restrict__ b_beta,
                                               const int* __restrict__ nact, int t,
                                               float* __restrict__ dec_proj,
                                               float* __restrict__ gate_raw) {
  int nact_t = nact[t];
  int mb = blockIdx.y * 32;
  if (mb >= nact_t) return;
  int lane = threadIdx.x;
  int lr = lane & 15, lg = lane >> 4;
  int nb = blockIdx.x * 32;
  f32x4 acc[2][2] = {};
  const u16* a0 = hb + (size_t)(mb + lr) * ND + lg * 8;
  const u16* a1 = a0 + 16 * ND;
  const u16* b0 = BT + (size_t)(nb + lr) * ND + lg * 8;
  const u16* b1 = b0 + 16 * ND;
#pragma unroll 4
  for (int k0 = 0; k0 < ND; k0 += 32) {
    bf16x8 af0 = *(const bf16x8*)(a0 + k0);
    bf16x8 af1 = *(const bf16x8*)(a1 + k0);
    bf16x8 bv0 = *(const bf16x8*)(b0 + k0);
    bf16x8 bv1 = *(const bf16x8*)(b1 + k0);
    acc[0][0] = MFMA16(af0, bv0, acc[0][0], 0, 0, 0);
    acc[1][0] = MFMA16(af1, bv0, acc[1][0], 0, 0, 0);
    acc[0][1] = MFMA16(af0, bv1, acc[0][1], 0, 0, 0);
    acc[1][1] = MFMA16(af1, bv1, acc[1][1], 0, 0, 0);
  }
#pragma unroll
  for (int mt = 0; mt < 2; ++mt)
#pragma unroll
    for (int nt = 0; nt < 2; ++nt)
#pragma unroll
      for (int j = 0; j < 4; ++j) {
        int row = mb + mt * 16 + lg * 4 + j;
        int n = nb + nt * 16 + lr;
        if (n < NA)
          dec_proj[(size_t)row * NA + n] = acc[mt][nt][j] + b_dec[n];
        else
          gate_raw[(size_t)row * NENC + (n - NA)] = acc[mt][nt][j] + b_beta[n - NA];
      }
}

// ---------------- kSAX: scores+softmax (x4 redundant) + attw 512-col slice ----------------
__global__ __launch_bounds__(256) void kSAX(const u16* __restrict__ featsb,
                                            const u16* __restrict__ encb,
                                            const float* __restrict__ dec_proj,
                                            const float* __restrict__ gate_raw,
                                            const float* __restrict__ w_full,
                                            const float* __restrict__ b_full,
                                            const int* __restrict__ nact, int t,
                                            u16* __restrict__ xh_w,
                                            float* __restrict__ out_alph) {
  int b = blockIdx.x, r = blockIdx.y, tid = threadIdx.x;
  if (b >= nact[t]) return;
  __shared__ float s_dp[NA], s_wf[NA], s_al[NP + 12], red[16];
  for (int i = tid; i < NA; i += 256) { s_dp[i] = dec_proj[(size_t)b * NA + i]; s_wf[i] = w_full[i]; }
  __syncthreads();
  int wave = tid >> 6, lane = tid & 63;
  float bf_ = b_full[0];
  for (int p = wave; p < NP; p += 4) {
    const u16* ep = encb + ((size_t)b * NP + p) * NA + lane * 8;
    u16x8 v = *(const u16x8*)ep;
    float acc = 0.0f;
#pragma unroll
    for (int j = 0; j < 8; ++j) {
      int a = lane * 8 + j;
      float vv = b2f(v[j]) + s_dp[a];
      acc += fmaxf(vv, 0.0f) * s_wf[a];
    }
#pragma unroll
    for (int off = 32; off; off >>= 1) acc += __shfl_down(acc, off);
    if (lane == 0) s_al[p] = acc + bf_;
  }
  __syncthreads();
  float mx = -3.4e38f;
  for (int p = tid; p < NP; p += 256) mx = fmaxf(mx, s_al[p]);
#pragma unroll
  for (int off = 32; off; off >>= 1) mx = fmaxf(mx, __shfl_down(mx, off));
  if (lane == 0) red[wave] = mx;
  __syncthreads();
  if (tid == 0) red[0] = fmaxf(fmaxf(red[0], red[1]), fmaxf(red[2], red[3]));
  __syncthreads();
  float m2v = red[0];
  float sm = 0.0f;
  for (int p = tid; p < NP; p += 256) { float e = __expf(s_al[p] - m2v); s_al[p] = e; sm += e; }
#pragma unroll
  for (int off = 32; off; off >>= 1) sm += __shfl_down(sm, off);
  if (lane == 0) red[8 + wave] = sm;
  __syncthreads();
  if (tid == 0) red[8] = 1.0f / (red[8] + red[9] + red[10] + red[11]);
  __syncthreads();
  float inv = red[8];
  for (int p = tid; p < NP; p += 256) {
    float al = s_al[p] * inv;
    s_al[p] = al;
    if (r == 0) out_alph[((size_t)b * NT + t) * NP + p] = al;
  }
  __syncthreads();
  // attw for cols [r*512, r*512+512): 2 cols/thread, fused beta-gate
  int e0 = r * 512 + tid * 2;
  float ac0 = 0.0f, ac1 = 0.0f;
  const u16* fb = featsb + (size_t)b * NP * NENC + e0;
#pragma unroll 4
  for (int p = 0; p < NP; ++p) {
    unsigned int v = *(const unsigned int*)(fb + (size_t)p * NENC);
    float al = s_al[p];
    ac0 += al * __uint_as_float(v << 16);
    ac1 += al * __uint_as_float(v & 0xffff0000u);
  }
  float g0 = sigmoidf_(gate_raw[(size_t)b * NENC + e0]);
  float g1 = sigmoidf_(gate_raw[(size_t)b * NENC + e0 + 1]);
  unsigned int wo = (unsigned int)f2b(ac0 * g0) | ((unsigned int)f2b(ac1 * g1) << 16);
  *(unsigned int*)(xh_w + (size_t)b * KXH2 + e0) = wo;
}

// ---------------- kGatesLstm: 32x32 tile/block, 8-way K-split + LSTM epilogue ----------------
__global__ __launch_bounds__(1024) void kGatesLstm(const u16* __restrict__ xh_r,
                                                   const u16* __restrict__ WifgoT2, // [2048][2560]
                                                   const u16* __restrict__ embAll,
                                                   const float* __restrict__ b_ih,
                                                   const float* __restrict__ b_hh,
                                                   const int* __restrict__ nact, int t,
                                                   float* __restrict__ cst,
                                                   u16* __restrict__ hb,
                                                   u16* __restrict__ hnewAll_t,
                                                   u16* __restrict__ xh_w) {
  __shared__ float smem[8 * 32 * 33];
  int nact_t = nact[t];
  int tid = threadIdx.x;
  int w = tid >> 6, lane = tid & 63;
  int lr = lane & 15, lg = lane >> 4;
  int rt = blockIdx.x & 3, ct = blockIdx.x >> 2;   // 4 Mtiles x 64 Ntiles
  int mb = rt * 32, nb = ct * 32;
  int kq = w >> 1, mh = w & 1;                     // 8 K-splits x 2 M-halves
  if (mb < nact_t) {
    f32x4 acc0 = {}, acc1 = {};
    const u16* pa = xh_r + (size_t)(mb + mh * 16 + lr) * KXH2 + kq * 320 + lg * 8;
    const u16* pb0 = WifgoT2 + (size_t)(nb + lr) * KXH2 + kq * 320 + lg * 8;
    const u16* pb1 = pb0 + (size_t)16 * KXH2;
#pragma unroll
    for (int k0 = 0; k0 < 320; k0 += 32) {
      bf16x8 af = *(const bf16x8*)(pa + k0);
      bf16x8 bv0 = *(const bf16x8*)(pb0 + k0);
      bf16x8 bv1 = *(const bf16x8*)(pb1 + k0);
      acc0 = MFMA16(af, bv0, acc0, 0, 0, 0);
      acc1 = MFMA16(af, bv1, acc1, 0, 0, 0);
    }
#pragma unroll
    for (int j = 0; j < 4; ++j) {
      int rr = kq * 32 + mh * 16 + lg * 4 + j;
      smem[rr * 33 + lr] = acc0[j];
      smem[rr * 33 + 16 + lr] = acc1[j];
    }
  }
  __syncthreads();
  if (tid < 256) {
    int row = tid >> 3, dl = tid & 7;
    int grow = mb + row;
    int d = ct * 8 + dl;
    size_t off = (size_t)grow * ND + d;
    if (grow < nact_t) {
      float g4[4];
#pragma unroll
      for (int g = 0; g < 4; ++g) {
        int col = dl * 4 + g;
        float s = 0.0f;
#pragma unroll
        for (int q = 0; q < 8; ++q) s += smem[(q * 32 + row) * 33 + col];
        s += b2f(embAll[((size_t)t * NB + grow) * NENC + nb + col]);
        g4[g] = s;
      }
      float gi = g4[0] + b_ih[d] + b_hh[d];
      float gf = g4[1] + b_ih[ND + d] + b_hh[ND + d];
      float gg = g4[2] + b_ih[2 * ND + d] + b_hh[2 * ND + d];
      float go = g4[3] + b_ih[3 * ND + d] + b_hh[3 * ND + d];
      float cn = sigmoidf_(gf) * cst[off] + sigmoidf_(gi) * tanhf(gg);
      float hn = sigmoidf_(go) * tanhf(cn);
      u16 hv = f2b(hn);
      cst[off] = cn;
      hb[off] = hv;
      hnewAll_t[off] = hv;
      xh_w[(size_t)grow * KXH2 + NENC + d] = hv;
    } else {
      xh_w[(size_t)grow * KXH2 + NENC + d] = hb[off];
    }
  }
}

// ---------------- batched preds GEMM, t-tiled for WfcT reuse ----------------
__global__ __launch_bounds__(256) void kPredsAllT(const u16* __restrict__ hnewAll,
                                                  const u16* __restrict__ BT,
                                                  const float* __restrict__ b_fc,
                                                  const int* __restrict__ nact,
                                                  float* __restrict__ out_pred) {
  int nb = blockIdx.x * 64;
  int w = threadIdx.x >> 6, lane = threadIdx.x & 63;
  int lr = lane & 15, lg = lane >> 4;
  int mb = w * 32;
  const u16* b0 = BT + (size_t)(nb + lr) * ND + lg * 8;
#pragma unroll
  for (int ti = 0; ti < 4; ++ti) {
    int t = blockIdx.y * 4 + ti;
    if (t >= NT) break;
    int nact_t = nact[t];
    f32x4 acc[2][4] = {};
    if (mb < nact_t) {
      const u16* a0 = hnewAll + (size_t)t * NB * ND + (size_t)(mb + lr) * ND + lg * 8;
      const u16* a1 = a0 + 16 * ND;
      for (int k0 = 0; k0 < ND; k0 += 32) {
        bf16x8 af0 = *(const bf16x8*)(a0 + k0);
        bf16x8 af1 = *(const bf16x8*)(a1 + k0);
#pragma unroll
        for (int nt = 0; nt < 4; ++nt) {
          bf16x8 bf = *(const bf16x8*)(b0 + (size_t)nt * 16 * ND + k0);
          acc[0][nt] = MFMA16(af0, bf, acc[0][nt], 0, 0, 0);
          acc[1][nt] = MFMA16(af1, bf, acc[1][nt], 0, 0, 0);
        }
      }
    }
#pragma unroll
    for (int mt = 0; mt < 2; ++mt)
#pragma unroll
      for (int nt = 0; nt < 4; ++nt)
#pragma unroll
        for (int j = 0; j < 4; ++j) {
          int gn = nb + nt * 16 + lr;
          if (gn < NV) {
            int row = mb + mt * 16 + lg * 4 + j;
            float v = (row < nact_t) ? (acc[mt][nt][j] + b_fc[gn]) : 0.0f;
            __builtin_nontemporal_store(v, &out_pred[((size_t)row * NT + t) * NV + gn]);
          }
        }
  }
}

extern "C" void kernel_launch(void* const* d_in, const int* in_sizes, int n_in,
                              void* d_out, int out_size, void* d_ws, size_t ws_size,
                              hipStream_t stream) {
  (void)in_sizes; (void)n_in; (void)out_size; (void)ws_size;
  const float* features  = (const float*)d_in[0];
  const int*   captions  = (const int*)d_in[1];
  const int*   cap_len   = (const int*)d_in[2];
  const float* emb       = (const float*)d_in[3];
  const float* W_enc_att = (const float*)d_in[4];
  const float* b_enc_att = (const float*)d_in[5];
  const float* W_dec_att = (const float*)d_in[6];
  const float* b_dec_att = (const float*)d_in[7];
  const float* w_full    = (const float*)d_in[8];
  const float* b_full    = (const float*)d_in[9];
  const float* W_h0      = (const float*)d_in[10];
  const float* b_h0      = (const float*)d_in[11];
  const float* W_c0      = (const float*)d_in[12];
  const float* b_c0      = (const float*)d_in[13];
  const float* W_beta    = (const float*)d_in[14];
  const float* b_beta    = (const float*)d_in[15];
  const float* W_ih      = (const float*)d_in[16];
  const float* b_ih      = (const float*)d_in[17];
  const float* W_hh      = (const float*)d_in[18];
  const float* b_hh      = (const float*)d_in[19];
  const float* W_fc      = (const float*)d_in[20];
  const float* b_fc      = (const float*)d_in[21];

  float* out      = (float*)d_out;
  float* out_pred = out;
  float* out_cap  = out_pred + (size_t)NB * NT * NV;
  float* out_dlen = out_cap + (size_t)NB * NL;
  float* out_alph = out_dlen + NB;

  char* p = (char*)d_ws;
  auto alloc = [&](size_t nbytes) { void* r = (void*)p; p += (nbytes + 255) & ~(size_t)255; return r; };
  int*   order    = (int*)alloc(NB * 4);
  int*   nact     = (int*)alloc(NT * 4);
  float* eo       = (float*)alloc((size_t)NB * NENC * 4);
  float* c        = (float*)alloc((size_t)NB * ND * 4);
  u16*   hb       = (u16*)alloc((size_t)NB * ND * 2);
  u16*   xh0      = (u16*)alloc((size_t)NB * KXH2 * 2);
  u16*   xh1      = (u16*)alloc((size_t)NB * KXH2 * 2);
  u16*   hnewAll  = (u16*)alloc((size_t)NT * NB * ND * 2);
  float* dec_proj = (float*)alloc((size_t)NB * NA * 4);
  float* gate_raw = (float*)alloc((size_t)NB * NENC * 4);
  u16*   featsb   = (u16*)alloc((size_t)NB * NP * NENC * 2);
  u16*   encb     = (u16*)alloc((size_t)NB * NP * NA * 2);
  u16*   WencT    = (u16*)alloc((size_t)NA * NENC * 2);
  u16*   WdgT     = (u16*)alloc((size_t)(NA + NENC) * ND * 2);
  u16*   WihTopT  = (u16*)alloc((size_t)NENC * NE * 2);
  u16*   WifgoT2  = (u16*)alloc((size_t)NENC * KXH2 * 2);
  u16*   WfcT     = (u16*)alloc((size_t)NVPAD * ND * 2);
  u16*   embA     = (u16*)alloc((size_t)NT * NB * NE * 2);
  u16*   embAll   = (u16*)alloc((size_t)NT * NB * NENC * 2);

  kSort<<<1, NB, 0, stream>>>(cap_len, captions, order, nact, out_cap, out_dlen);
  kAlphaZero<<<NT, 256, 0, stream>>>(nact, out_alph);
  kFeats<<<dim3(NP, NB), 256, 0, stream>>>(features, order, featsb);
  kTWenc<<<NA, 256, 0, stream>>>(W_enc_att, WencT);
  kTdg<<<NA + NENC, 256, 0, stream>>>(W_dec_att, W_beta, WdgT);
  kTWihTop<<<NENC, 256, 0, stream>>>(W_ih, WihTopT);
  kTifgo2<<<NENC, 256, 0, stream>>>(W_ih, W_hh, WifgoT2);
  kTfc<<<NVPAD, 256, 0, stream>>>(W_fc, WfcT);
  kEmbA<<<dim3(NT, NB), 256, 0, stream>>>(emb, captions, order, embA);
  kEmbGemm<<<dim3(NENC / 64, NT), 256, 0, stream>>>(embA, WihTopT, embAll);
  kEo<<<dim3(NENC / 256, NB), 256, 0, stream>>>(featsb, eo);
  kInitHC<<<dim3(ND / 256, NB, 2), 256, 0, stream>>>(eo, W_h0, b_h0, W_c0, b_c0, hb, xh0, c);
  kEncProj<<<784, 256, 0, stream>>>(featsb, WencT, b_enc_att, encb);

  for (int t = 0; t < NT; ++t) {
    u16* xh_r = (t & 1) ? xh1 : xh0;
    u16* xh_w = (t & 1) ? xh0 : xh1;
    kDecGate<<<dim3((NA + NENC) / 32, 4), 64, 0, stream>>>(hb, WdgT, b_dec_att, b_beta,
                                                           nact, t, dec_proj, gate_raw);
    kSAX<<<dim3(NB, 4), 256, 0, stream>>>(featsb, encb, dec_proj, gate_raw, w_full, b_full,
                                          nact, t, xh_r, out_alph);
    kGatesLstm<<<256, 1024, 0, stream>>>(xh_r, WifgoT2, embAll, b_ih, b_hh, nact, t,
                                         c, hb, hnewAll + (size_t)t * NB * ND, xh_w);
  }
  kPredsAllT<<<dim3(NVPAD / 64, (NT + 3) / 4), 256, 0, stream>>>(hnewAll, WfcT, b_fc, nact, out_pred);
}

// Round 9
// 4507.630 us; speedup vs baseline: 1.7703x; 1.0245x over previous
//
#include <hip/hip_runtime.h>
#include <math.h>

#define NB 128
#define NP 196
#define NENC 2048
#define NE 512
#define ND 512
#define NA 512
#define NV 10000
#define NVPAD 10112
#define NL 52
#define NT 51
#define KXH2 2560   // [attw 2048 | h 512]

typedef unsigned short u16;
typedef __attribute__((ext_vector_type(8))) short bf16x8;
typedef __attribute__((ext_vector_type(8))) unsigned short u16x8;
typedef __attribute__((ext_vector_type(4))) float f32x4;

#define MFMA16 __builtin_amdgcn_mfma_f32_16x16x32_bf16

__device__ __forceinline__ float sigmoidf_(float v) { return 1.0f / (1.0f + __expf(-v)); }
__device__ __forceinline__ float b2f(u16 u) { return __uint_as_float(((unsigned int)u) << 16); }
__device__ __forceinline__ u16 f2b(float f) {
  unsigned int u = __float_as_uint(f);
  unsigned int r = (u + 0x7FFFu + ((u >> 16) & 1u)) >> 16;
  return (u16)r;
}

// ---------------- sort + nact ----------------
__global__ void kSort(const int* __restrict__ cap_len, const int* __restrict__ captions,
                      int* __restrict__ order, int* __restrict__ nact,
                      float* __restrict__ out_cap, float* __restrict__ out_dlen) {
  __shared__ int lens[NB];
  __shared__ int s_dl[NB];
  int tid = threadIdx.x;
  lens[tid] = cap_len[tid];
  __syncthreads();
  int li = lens[tid];
  int r = 0;
  for (int j = 0; j < NB; ++j) {
    int lj = lens[j];
    if (lj > li || (lj == li && j < tid)) r++;
  }
  order[r] = tid;
  s_dl[r] = li - 1;
  out_dlen[r] = (float)(li - 1);
  for (int l = 0; l < NL; ++l)
    out_cap[(size_t)r * NL + l] = (float)captions[(size_t)tid * NL + l];
  __syncthreads();
  if (tid < NT) {
    int cnt = 0;
    for (int j = 0; j < NB; ++j) cnt += (s_dl[j] > tid) ? 1 : 0;
    nact[tid] = cnt;
  }
}

__global__ void kAlphaZero(const int* __restrict__ nact, float* __restrict__ out_alph) {
  int t = blockIdx.x;
  int n0 = nact[t];
  int cnt = (NB - n0) * NP;
  for (int i = threadIdx.x; i < cnt; i += 256) {
    int b = n0 + i / NP;
    int p = i - (i / NP) * NP;
    out_alph[((size_t)b * NT + t) * NP + p] = 0.0f;
  }
}

// ---------------- features gather + bf16 ----------------
__global__ void kFeats(const float* __restrict__ features, const int* __restrict__ order,
                       u16* __restrict__ featsb) {
  int p = blockIdx.x, b = blockIdx.y, tid = threadIdx.x;
  const float* src = features + ((size_t)order[b] * NP + p) * NENC + tid * 8;
  u16* dst = featsb + ((size_t)b * NP + p) * NENC + tid * 8;
  float4 v0 = *(const float4*)src;
  float4 v1 = *(const float4*)(src + 4);
  u16x8 o;
  o[0] = f2b(v0.x); o[1] = f2b(v0.y); o[2] = f2b(v0.z); o[3] = f2b(v0.w);
  o[4] = f2b(v1.x); o[5] = f2b(v1.y); o[6] = f2b(v1.z); o[7] = f2b(v1.w);
  *(u16x8*)dst = o;
}

// ---------------- unified LDS-tiled transpose: dst[n][k] = bf16(src(k, n)) ----------------
// mode 0: Wenc  A[k*NA+n]                              K=2048 N=512
// mode 1: dg    n<NA ? A[k*NA+n] : B[k*NENC+(n-NA)]    K=512  N=2560
// mode 2: ihtop A[k*(4*ND) + (n&3)*ND+(n>>2)]          K=512  N=2048
// mode 3: ifgo2 k<NENC ? A[(NE+k)*(4*ND)+cm] : B[(k-NENC)*(4*ND)+cm]  K=2560 N=2048
// mode 4: fc    n<NV ? A[k*NV+n] : 0                   K=512  N=10112
// mode 5: hc0   n<NA ? A[k*ND+n] : B[k*ND+(n-NA)]      K=2048 N=1024
__device__ __forceinline__ float tfetch(int mode, int k, int n,
                                        const float* __restrict__ A,
                                        const float* __restrict__ B) {
  switch (mode) {
    case 0: return A[(size_t)k * NA + n];
    case 1: return (n < NA) ? A[(size_t)k * NA + n] : B[(size_t)k * NENC + (n - NA)];
    case 2: return A[(size_t)k * (4 * ND) + (n & 3) * ND + (n >> 2)];
    case 3: {
      int col = (n & 3) * ND + (n >> 2);
      return (k < NENC) ? A[(size_t)(NE + k) * (4 * ND) + col]
                        : B[(size_t)(k - NENC) * (4 * ND) + col];
    }
    case 4: return (n < NV) ? A[(size_t)k * NV + n] : 0.0f;
    default: return (n < NA) ? A[(size_t)k * ND + n] : B[(size_t)k * ND + (n - NA)];
  }
}

__global__ __launch_bounds__(256) void kTrans(const float* __restrict__ A,
                                              const float* __restrict__ B,
                                              u16* __restrict__ dst,
                                              int K, int N, int mode) {
  __shared__ u16 T[32][136];
  int n0 = blockIdx.x * 32, k0 = blockIdx.y * 128;
  int tid = threadIdx.x;
  int c = tid & 31, kr = tid >> 5;
#pragma unroll
  for (int pass = 0; pass < 16; ++pass) {
    int kl = pass * 8 + kr;
    T[c][kl] = f2b(tfetch(mode, k0 + kl, n0 + c, A, B));
  }
  __syncthreads();
  int row = tid >> 3, seg = tid & 7;
  u16x8 v0, v1;
#pragma unroll
  for (int j = 0; j < 8; ++j) { v0[j] = T[row][seg * 16 + j]; v1[j] = T[row][seg * 16 + 8 + j]; }
  *(u16x8*)&dst[(size_t)(n0 + row) * K + k0 + seg * 16] = v0;
  *(u16x8*)&dst[(size_t)(n0 + row) * K + k0 + seg * 16 + 8] = v1;
}

// ---------------- embA: gather caption embeddings (bf16) ----------------
__global__ void kEmbA(const float* __restrict__ emb, const int* __restrict__ captions,
                      const int* __restrict__ order, u16* __restrict__ embA) {
  int t = blockIdx.x, b = blockIdx.y;
  int tok = captions[(size_t)order[b] * NL + t];
  int i = threadIdx.x * 2;
  float2 v = *(const float2*)(emb + (size_t)tok * NE + i);
  unsigned int w0 = (unsigned int)f2b(v.x) | ((unsigned int)f2b(v.y) << 16);
  *(unsigned int*)(embA + ((size_t)t * NB + b) * NE + i) = w0;
}

// ---------------- embAll = embA @ WihTopT (bf16 out, K=512) ----------------
__global__ __launch_bounds__(256) void kEmbGemm(const u16* __restrict__ A,
                                                const u16* __restrict__ BT,
                                                u16* __restrict__ D) {
  int w = threadIdx.x >> 6, lane = threadIdx.x & 63;
  int lr = lane & 15, lg = lane >> 4;
  int mb = blockIdx.y * 128 + w * 32;
  int nb = blockIdx.x * 64;
  f32x4 acc[2][4] = {};
  const u16* a0 = A + (size_t)(mb + lr) * NE + lg * 8;
  const u16* a1 = a0 + 16 * NE;
  const u16* b0 = BT + (size_t)(nb + lr) * NE + lg * 8;
  for (int k0 = 0; k0 < NE; k0 += 32) {
    bf16x8 af0 = *(const bf16x8*)(a0 + k0);
    bf16x8 af1 = *(const bf16x8*)(a1 + k0);
#pragma unroll
    for (int nt = 0; nt < 4; ++nt) {
      bf16x8 bf = *(const bf16x8*)(b0 + (size_t)nt * 16 * NE + k0);
      acc[0][nt] = MFMA16(af0, bf, acc[0][nt], 0, 0, 0);
      acc[1][nt] = MFMA16(af1, bf, acc[1][nt], 0, 0, 0);
    }
  }
#pragma unroll
  for (int mt = 0; mt < 2; ++mt)
#pragma unroll
    for (int nt = 0; nt < 4; ++nt)
#pragma unroll
      for (int j = 0; j < 4; ++j) {
        int row = mb + mt * 16 + lg * 4 + j;
        int col = nb + nt * 16 + lr;
        D[(size_t)row * NENC + col] = f2b(acc[mt][nt][j]);
      }
}

// ---------------- eo = mean over P (bf16 out) ----------------
__global__ void kEo(const u16* __restrict__ featsb, u16* __restrict__ eob) {
  int e = blockIdx.x * 256 + threadIdx.x;
  int b = blockIdx.y;
  const u16* f = featsb + (size_t)b * NP * NENC + e;
  float s = 0.0f;
  for (int p = 0; p < NP; ++p) s += b2f(f[(size_t)p * NENC]);
  eob[(size_t)b * NENC + e] = f2b(s * (1.0f / NP));
}

// ---------------- h0/c0 via MFMA: [128x2048] @ WhcT[1024][2048] ----------------
__global__ __launch_bounds__(64) void kHC0(const u16* __restrict__ eob,
                                           const u16* __restrict__ BT,
                                           const float* __restrict__ b_h0,
                                           const float* __restrict__ b_c0,
                                           u16* __restrict__ hb, u16* __restrict__ xh0,
                                           float* __restrict__ c) {
  int lane = threadIdx.x;
  int lr = lane & 15, lg = lane >> 4;
  int mb = blockIdx.y * 32, nb = blockIdx.x * 32;
  f32x4 acc[2][2] = {};
  const u16* a0 = eob + (size_t)(mb + lr) * NENC + lg * 8;
  const u16* a1 = a0 + 16 * NENC;
  const u16* b0 = BT + (size_t)(nb + lr) * NENC + lg * 8;
  const u16* b1 = b0 + 16 * NENC;
#pragma unroll 4
  for (int k0 = 0; k0 < NENC; k0 += 32) {
    bf16x8 af0 = *(const bf16x8*)(a0 + k0);
    bf16x8 af1 = *(const bf16x8*)(a1 + k0);
    bf16x8 bv0 = *(const bf16x8*)(b0 + k0);
    bf16x8 bv1 = *(const bf16x8*)(b1 + k0);
    acc[0][0] = MFMA16(af0, bv0, acc[0][0], 0, 0, 0);
    acc[1][0] = MFMA16(af1, bv0, acc[1][0], 0, 0, 0);
    acc[0][1] = MFMA16(af0, bv1, acc[0][1], 0, 0, 0);
    acc[1][1] = MFMA16(af1, bv1, acc[1][1], 0, 0, 0);
  }
#pragma unroll
  for (int mt = 0; mt < 2; ++mt)
#pragma unroll
    for (int nt = 0; nt < 2; ++nt)
#pragma unroll
      for (int j = 0; j < 4; ++j) {
        int row = mb + mt * 16 + lg * 4 + j;
        int n = nb + nt * 16 + lr;
        if (n < NA) {
          u16 hv = f2b(acc[mt][nt][j] + b_h0[n]);
          hb[(size_t)row * ND + n] = hv;
          xh0[(size_t)row * KXH2 + NENC + n] = hv;
        } else {
          c[(size_t)row * ND + (n - NA)] = acc[mt][nt][j] + b_c0[n - NA];
        }
      }
}

// ---------------- enc_proj: double-buffered LDS A, one barrier/iter ----------------
__global__ __launch_bounds__(256) void kEncProj(const u16* __restrict__ A,
                                                const u16* __restrict__ BT,
                                                const float* __restrict__ bias,
                                                u16* __restrict__ D) {
  __shared__ u16 As[2][128][72];
  int bid = blockIdx.x;         // 784 = 196 Mtiles x 4 Ntiles
  int mt = bid >> 2, ntile = bid & 3;
  int mb = mt * 128, nb = ntile * 128;
  int tid = threadIdx.x;
  int w = tid >> 6, lane = tid & 63;
  int lr = lane & 15, lg = lane >> 4;

  int arow[4], akp[4];
  const u16* aptr[4];
#pragma unroll
  for (int i = 0; i < 4; ++i) {
    int idx = i * 256 + tid;
    arow[i] = idx >> 3;
    akp[i] = idx & 7;
    aptr[i] = A + (size_t)(mb + arow[i]) * NENC + akp[i] * 8;
  }
  u16x8 s0 = *(const u16x8*)(aptr[0]);
  u16x8 s1 = *(const u16x8*)(aptr[1]);
  u16x8 s2 = *(const u16x8*)(aptr[2]);
  u16x8 s3 = *(const u16x8*)(aptr[3]);
  *(u16x8*)&As[0][arow[0]][akp[0] * 8] = s0;
  *(u16x8*)&As[0][arow[1]][akp[1] * 8] = s1;
  *(u16x8*)&As[0][arow[2]][akp[2] * 8] = s2;
  *(u16x8*)&As[0][arow[3]][akp[3] * 8] = s3;

  f32x4 acc[2][8] = {};
  const u16* bbase = BT + (size_t)(nb + lr) * NENC + lg * 8;
  int cur = 0;
  int r0 = w * 32 + lr;

  for (int k0 = 0; k0 < NENC; k0 += 64) {
    __syncthreads();                       // As[cur] visible; As[cur^1] consumers done
    bool more = (k0 + 64 < NENC);
    if (more) {                            // issue AFTER barrier -> flies under compute
      s0 = *(const u16x8*)(aptr[0] + k0 + 64);
      s1 = *(const u16x8*)(aptr[1] + k0 + 64);
      s2 = *(const u16x8*)(aptr[2] + k0 + 64);
      s3 = *(const u16x8*)(aptr[3] + k0 + 64);
    }
#pragma unroll
    for (int kh = 0; kh < 2; ++kh) {
      bf16x8 af0 = *(const bf16x8*)&As[cur][r0][kh * 32 + lg * 8];
      bf16x8 af1 = *(const bf16x8*)&As[cur][r0 + 16][kh * 32 + lg * 8];
#pragma unroll
      for (int nt = 0; nt < 8; ++nt) {
        bf16x8 bf = *(const bf16x8*)(bbase + (size_t)nt * 16 * NENC + k0 + kh * 32);
        acc[0][nt] = MFMA16(af0, bf, acc[0][nt], 0, 0, 0);
        acc[1][nt] = MFMA16(af1, bf, acc[1][nt], 0, 0, 0);
      }
    }
    if (more) {
      *(u16x8*)&As[cur ^ 1][arow[0]][akp[0] * 8] = s0;
      *(u16x8*)&As[cur ^ 1][arow[1]][akp[1] * 8] = s1;
      *(u16x8*)&As[cur ^ 1][arow[2]][akp[2] * 8] = s2;
      *(u16x8*)&As[cur ^ 1][arow[3]][akp[3] * 8] = s3;
    }
    cur ^= 1;
  }
#pragma unroll
  for (int m2 = 0; m2 < 2; ++m2)
#pragma unroll
    for (int nt = 0; nt < 8; ++nt)
#pragma unroll
      for (int j = 0; j < 4; ++j) {
        int row = mb + w * 32 + m2 * 16 + lg * 4 + j;
        int col = nb + nt * 16 + lr;
        D[(size_t)row * NA + col] = f2b(acc[m2][nt][j] + bias[col]);
      }
}

// ---------------- kDecGate: dec_proj & gate_raw (MFMA, 32x32, 1-wave blocks) ----------------
__global__ __launch_bounds__(64) void kDecGate(const u16* __restrict__ hb,
                                               const u16* __restrict__ BT,   // [2560][512]
                                               const float* __restrict__ b_dec,
                                               const float* __restrict__ b_beta,
                                               const int* __restrict__ nact, int t,
                                               float* __restrict__ dec_proj,
                                               float* __restrict__ gate_raw) {
  int nact_t = nact[t];
  int mb = blockIdx.y * 32;
  if (mb >= nact_t) return;
  int lane = threadIdx.x;
  int lr = lane & 15, lg = lane >> 4;
  int nb = blockIdx.x * 32;
  f32x4 acc[2][2] = {};
  const u16* a0 = hb + (size_t)(mb + lr) * ND + lg * 8;
  const u16* a1 = a0 + 16 * ND;
  const u16* b0 = BT + (size_t)(nb + lr) * ND + lg * 8;
  const u16* b1 = b0 + 16 * ND;
#pragma unroll 4
  for (int k0 = 0; k0 < ND; k0 += 32) {
    bf16x8 af0 = *(const bf16x8*)(a0 + k0);
    bf16x8 af1 = *(const bf16x8*)(a1 + k0);
    bf16x8 bv0 = *(const bf16x8*)(b0 + k0);
    bf16x8 bv1 = *(const bf16x8*)(b1 + k0);
    acc[0][0] = MFMA16(af0, bv0, acc[0][0], 0, 0, 0);
    acc[1][0] = MFMA16(af1, bv0, acc[1][0], 0, 0, 0);
    acc[0][1] = MFMA16(af0, bv1, acc[0][1], 0, 0, 0);
    acc[1][1] = MFMA16(af1, bv1, acc[1][1], 0, 0, 0);
  }
#pragma unroll
  for (int mt = 0; mt < 2; ++mt)
#pragma unroll
    for (int nt = 0; nt < 2; ++nt)
#pragma unroll
      for (int j = 0; j < 4; ++j) {
        int row = mb + mt * 16 + lg * 4 + j;
        int n = nb + nt * 16 + lr;
        if (n < NA)
          dec_proj[(size_t)row * NA + n] = acc[mt][nt][j] + b_dec[n];
        else
          gate_raw[(size_t)row * NENC + (n - NA)] = acc[mt][nt][j] + b_beta[n - NA];
      }
}

// ---------------- kSAX: scores+softmax (x4 redundant) + attw 512-col slice ----------------
__global__ __launch_bounds__(256) void kSAX(const u16* __restrict__ featsb,
                                            const u16* __restrict__ encb,
                                            const float* __restrict__ dec_proj,
                                            const float* __restrict__ gate_raw,
                                            const float* __restrict__ w_full,
                                            const float* __restrict__ b_full,
                                            const int* __restrict__ nact, int t,
                                            u16* __restrict__ xh_w,
                                            float* __restrict__ out_alph) {
  int b = blockIdx.x, r = blockIdx.y, tid = threadIdx.x;
  if (b >= nact[t]) return;
  __shared__ float s_dp[NA], s_wf[NA], s_al[NP + 12], red[16];
  for (int i = tid; i < NA; i += 256) { s_dp[i] = dec_proj[(size_t)b * NA + i]; s_wf[i] = w_full[i]; }
  __syncthreads();
  int wave = tid >> 6, lane = tid & 63;
  float bf_ = b_full[0];
  for (int p = wave; p < NP; p += 4) {
    const u16* ep = encb + ((size_t)b * NP + p) * NA + lane * 8;
    u16x8 v = *(const u16x8*)ep;
    float acc = 0.0f;
#pragma unroll
    for (int j = 0; j < 8; ++j) {
      int a = lane * 8 + j;
      float vv = b2f(v[j]) + s_dp[a];
      acc += fmaxf(vv, 0.0f) * s_wf[a];
    }
#pragma unroll
    for (int off = 32; off; off >>= 1) acc += __shfl_down(acc, off);
    if (lane == 0) s_al[p] = acc + bf_;
  }
  __syncthreads();
  float mx = -3.4e38f;
  for (int p = tid; p < NP; p += 256) mx = fmaxf(mx, s_al[p]);
#pragma unroll
  for (int off = 32; off; off >>= 1) mx = fmaxf(mx, __shfl_down(mx, off));
  if (lane == 0) red[wave] = mx;
  __syncthreads();
  if (tid == 0) red[0] = fmaxf(fmaxf(red[0], red[1]), fmaxf(red[2], red[3]));
  __syncthreads();
  float m2v = red[0];
  float sm = 0.0f;
  for (int p = tid; p < NP; p += 256) { float e = __expf(s_al[p] - m2v); s_al[p] = e; sm += e; }
#pragma unroll
  for (int off = 32; off; off >>= 1) sm += __shfl_down(sm, off);
  if (lane == 0) red[8 + wave] = sm;
  __syncthreads();
  if (tid == 0) red[8] = 1.0f / (red[8] + red[9] + red[10] + red[11]);
  __syncthreads();
  float inv = red[8];
  for (int p = tid; p < NP; p += 256) {
    float al = s_al[p] * inv;
    s_al[p] = al;
    if (r == 0) out_alph[((size_t)b * NT + t) * NP + p] = al;
  }
  __syncthreads();
  int e0 = r * 512 + tid * 2;
  float ac0 = 0.0f, ac1 = 0.0f;
  const u16* fb = featsb + (size_t)b * NP * NENC + e0;
#pragma unroll 4
  for (int p = 0; p < NP; ++p) {
    unsigned int v = *(const unsigned int*)(fb + (size_t)p * NENC);
    float al = s_al[p];
    ac0 += al * __uint_as_float(v << 16);
    ac1 += al * __uint_as_float(v & 0xffff0000u);
  }
  float g0 = sigmoidf_(gate_raw[(size_t)b * NENC + e0]);
  float g1 = sigmoidf_(gate_raw[(size_t)b * NENC + e0 + 1]);
  unsigned int wo = (unsigned int)f2b(ac0 * g0) | ((unsigned int)f2b(ac1 * g1) << 16);
  *(unsigned int*)(xh_w + (size_t)b * KXH2 + e0) = wo;
}

// ---------------- kGatesLstm: 32x32 tile/block, 8-way K-split + LSTM epilogue ----------------
__global__ __launch_bounds__(1024) void kGatesLstm(const u16* __restrict__ xh_r,
                                                   const u16* __restrict__ WifgoT2, // [2048][2560]
                                                   const u16* __restrict__ embAll,
                                                   const float* __restrict__ b_ih,
                                                   const float* __restrict__ b_hh,
                                                   const int* __restrict__ nact, int t,
                                                   float* __restrict__ cst,
                                                   u16* __restrict__ hb,
                                                   u16* __restrict__ hnewAll_t,
                                                   u16* __restrict__ xh_w) {
  __shared__ float smem[8 * 32 * 33];
  int nact_t = nact[t];
  int tid = threadIdx.x;
  int w = tid >> 6, lane = tid & 63;
  int lr = lane & 15, lg = lane >> 4;
  int rt = blockIdx.x & 3, ct = blockIdx.x >> 2;   // 4 Mtiles x 64 Ntiles
  int mb = rt * 32, nb = ct * 32;
  int kq = w >> 1, mh = w & 1;                     // 8 K-splits x 2 M-halves
  if (mb < nact_t) {
    f32x4 acc0 = {}, acc1 = {};
    const u16* pa = xh_r + (size_t)(mb + mh * 16 + lr) * KXH2 + kq * 320 + lg * 8;
    const u16* pb0 = WifgoT2 + (size_t)(nb + lr) * KXH2 + kq * 320 + lg * 8;
    const u16* pb1 = pb0 + (size_t)16 * KXH2;
#pragma unroll
    for (int k0 = 0; k0 < 320; k0 += 32) {
      bf16x8 af = *(const bf16x8*)(pa + k0);
      bf16x8 bv0 = *(const bf16x8*)(pb0 + k0);
      bf16x8 bv1 = *(const bf16x8*)(pb1 + k0);
      acc0 = MFMA16(af, bv0, acc0, 0, 0, 0);
      acc1 = MFMA16(af, bv1, acc1, 0, 0, 0);
    }
#pragma unroll
    for (int j = 0; j < 4; ++j) {
      int rr = kq * 32 + mh * 16 + lg * 4 + j;
      smem[rr * 33 + lr] = acc0[j];
      smem[rr * 33 + 16 + lr] = acc1[j];
    }
  }
  __syncthreads();
  if (tid < 256) {
    int row = tid >> 3, dl = tid & 7;
    int grow = mb + row;
    int d = ct * 8 + dl;
    size_t off = (size_t)grow * ND + d;
    if (grow < nact_t) {
      float g4[4];
#pragma unroll
      for (int g = 0; g < 4; ++g) {
        int col = dl * 4 + g;
        float s = 0.0f;
#pragma unroll
        for (int q = 0; q < 8; ++q) s += smem[(q * 32 + row) * 33 + col];
        s += b2f(embAll[((size_t)t * NB + grow) * NENC + nb + col]);
        g4[g] = s;
      }
      float gi = g4[0] + b_ih[d] + b_hh[d];
      float gf = g4[1] + b_ih[ND + d] + b_hh[ND + d];
      float gg = g4[2] + b_ih[2 * ND + d] + b_hh[2 * ND + d];
      float go = g4[3] + b_ih[3 * ND + d] + b_hh[3 * ND + d];
      float cn = sigmoidf_(gf) * cst[off] + sigmoidf_(gi) * tanhf(gg);
      float hn = sigmoidf_(go) * tanhf(cn);
      u16 hv = f2b(hn);
      cst[off] = cn;
      hb[off] = hv;
      hnewAll_t[off] = hv;
      xh_w[(size_t)grow * KXH2 + NENC + d] = hv;
    } else {
      xh_w[(size_t)grow * KXH2 + NENC + d] = hb[off];
    }
  }
}

// ---------------- preds GEMM: grid (t fastest, n-tile slow) for B L2 reuse ----------------
__global__ __launch_bounds__(256) void kPredsAll2(const u16* __restrict__ hnewAll,
                                                  const u16* __restrict__ BT,
                                                  const float* __restrict__ b_fc,
                                                  const int* __restrict__ nact,
                                                  float* __restrict__ out_pred) {
  int t = blockIdx.x;              // fastest -> 51 consecutive blocks share B slice
  int nb = blockIdx.y * 64;
  int nact_t = nact[t];
  int w = threadIdx.x >> 6, lane = threadIdx.x & 63;
  int lr = lane & 15, lg = lane >> 4;
  int mb = w * 32;
  f32x4 acc[2][4] = {};
  if (mb < nact_t) {
    const u16* a0 = hnewAll + (size_t)t * NB * ND + (size_t)(mb + lr) * ND + lg * 8;
    const u16* a1 = a0 + 16 * ND;
    const u16* b0 = BT + (size_t)(nb + lr) * ND + lg * 8;
    for (int k0 = 0; k0 < ND; k0 += 32) {
      bf16x8 af0 = *(const bf16x8*)(a0 + k0);
      bf16x8 af1 = *(const bf16x8*)(a1 + k0);
#pragma unroll
      for (int nt = 0; nt < 4; ++nt) {
        bf16x8 bf = *(const bf16x8*)(b0 + (size_t)nt * 16 * ND + k0);
        acc[0][nt] = MFMA16(af0, bf, acc[0][nt], 0, 0, 0);
        acc[1][nt] = MFMA16(af1, bf, acc[1][nt], 0, 0, 0);
      }
    }
  }
#pragma unroll
  for (int mt = 0; mt < 2; ++mt)
#pragma unroll
    for (int nt = 0; nt < 4; ++nt)
#pragma unroll
      for (int j = 0; j < 4; ++j) {
        int gn = nb + nt * 16 + lr;
        if (gn < NV) {
          int row = mb + mt * 16 + lg * 4 + j;
          float v = (row < nact_t) ? (acc[mt][nt][j] + b_fc[gn]) : 0.0f;
          __builtin_nontemporal_store(v, &out_pred[((size_t)row * NT + t) * NV + gn]);
        }
      }
}

extern "C" void kernel_launch(void* const* d_in, const int* in_sizes, int n_in,
                              void* d_out, int out_size, void* d_ws, size_t ws_size,
                              hipStream_t stream) {
  (void)in_sizes; (void)n_in; (void)out_size; (void)ws_size;
  const float* features  = (const float*)d_in[0];
  const int*   captions  = (const int*)d_in[1];
  const int*   cap_len   = (const int*)d_in[2];
  const float* emb       = (const float*)d_in[3];
  const float* W_enc_att = (const float*)d_in[4];
  const float* b_enc_att = (const float*)d_in[5];
  const float* W_dec_att = (const float*)d_in[6];
  const float* b_dec_att = (const float*)d_in[7];
  const float* w_full    = (const float*)d_in[8];
  const float* b_full    = (const float*)d_in[9];
  const float* W_h0      = (const float*)d_in[10];
  const float* b_h0      = (const float*)d_in[11];
  const float* W_c0      = (const float*)d_in[12];
  const float* b_c0      = (const float*)d_in[13];
  const float* W_beta    = (const float*)d_in[14];
  const float* b_beta    = (const float*)d_in[15];
  const float* W_ih      = (const float*)d_in[16];
  const float* b_ih      = (const float*)d_in[17];
  const float* W_hh      = (const float*)d_in[18];
  const float* b_hh      = (const float*)d_in[19];
  const float* W_fc      = (const float*)d_in[20];
  const float* b_fc      = (const float*)d_in[21];

  float* out      = (float*)d_out;
  float* out_pred = out;
  float* out_cap  = out_pred + (size_t)NB * NT * NV;
  float* out_dlen = out_cap + (size_t)NB * NL;
  float* out_alph = out_dlen + NB;

  char* p = (char*)d_ws;
  auto alloc = [&](size_t nbytes) { void* r = (void*)p; p += (nbytes + 255) & ~(size_t)255; return r; };
  int*   order    = (int*)alloc(NB * 4);
  int*   nact     = (int*)alloc(NT * 4);
  u16*   eob      = (u16*)alloc((size_t)NB * NENC * 2);
  float* c        = (float*)alloc((size_t)NB * ND * 4);
  u16*   hb       = (u16*)alloc((size_t)NB * ND * 2);
  u16*   xh0      = (u16*)alloc((size_t)NB * KXH2 * 2);
  u16*   xh1      = (u16*)alloc((size_t)NB * KXH2 * 2);
  u16*   hnewAll  = (u16*)alloc((size_t)NT * NB * ND * 2);
  float* dec_proj = (float*)alloc((size_t)NB * NA * 4);
  float* gate_raw = (float*)alloc((size_t)NB * NENC * 4);
  u16*   featsb   = (u16*)alloc((size_t)NB * NP * NENC * 2);
  u16*   encb     = (u16*)alloc((size_t)NB * NP * NA * 2);
  u16*   WencT    = (u16*)alloc((size_t)NA * NENC * 2);
  u16*   WdgT     = (u16*)alloc((size_t)(NA + NENC) * ND * 2);
  u16*   WihTopT  = (u16*)alloc((size_t)NENC * NE * 2);
  u16*   WifgoT2  = (u16*)alloc((size_t)NENC * KXH2 * 2);
  u16*   WfcT     = (u16*)alloc((size_t)NVPAD * ND * 2);
  u16*   WhcT     = (u16*)alloc((size_t)1024 * NENC * 2);
  u16*   embA     = (u16*)alloc((size_t)NT * NB * NE * 2);
  u16*   embAll   = (u16*)alloc((size_t)NT * NB * NENC * 2);

  kSort<<<1, NB, 0, stream>>>(cap_len, captions, order, nact, out_cap, out_dlen);
  kAlphaZero<<<NT, 256, 0, stream>>>(nact, out_alph);
  kFeats<<<dim3(NP, NB), 256, 0, stream>>>(features, order, featsb);
  kTrans<<<dim3(512 / 32, 2048 / 128), 256, 0, stream>>>(W_enc_att, nullptr, WencT, 2048, 512, 0);
  kTrans<<<dim3(2560 / 32, 512 / 128), 256, 0, stream>>>(W_dec_att, W_beta, WdgT, 512, 2560, 1);
  kTrans<<<dim3(2048 / 32, 512 / 128), 256, 0, stream>>>(W_ih, nullptr, WihTopT, 512, 2048, 2);
  kTrans<<<dim3(2048 / 32, 2560 / 128), 256, 0, stream>>>(W_ih, W_hh, WifgoT2, 2560, 2048, 3);
  kTrans<<<dim3(NVPAD / 32, 512 / 128), 256, 0, stream>>>(W_fc, nullptr, WfcT, 512, NVPAD, 4);
  kTrans<<<dim3(1024 / 32, 2048 / 128), 256, 0, stream>>>(W_h0, W_c0, WhcT, 2048, 1024, 5);
  kEmbA<<<dim3(NT, NB), 256, 0, stream>>>(emb, captions, order, embA);
  kEmbGemm<<<dim3(NENC / 64, NT), 256, 0, stream>>>(embA, WihTopT, embAll);
  kEo<<<dim3(NENC / 256, NB), 256, 0, stream>>>(featsb, eob);
  kHC0<<<dim3(1024 / 32, NB / 32), 64, 0, stream>>>(eob, WhcT, b_h0, b_c0, hb, xh0, c);
  kEncProj<<<784, 256, 0, stream>>>(featsb, WencT, b_enc_att, encb);

  for (int t = 0; t < NT; ++t) {
    u16* xh_r = (t & 1) ? xh1 : xh0;
    u16* xh_w = (t & 1) ? xh0 : xh1;
    kDecGate<<<dim3((NA + NENC) / 32, 4), 64, 0, stream>>>(hb, WdgT, b_dec_att, b_beta,
                                                           nact, t, dec_proj, gate_raw);
    kSAX<<<dim3(NB, 4), 256, 0, stream>>>(featsb, encb, dec_proj, gate_raw, w_full, b_full,
                                          nact, t, xh_r, out_alph);
    kGatesLstm<<<256, 1024, 0, stream>>>(xh_r, WifgoT2, embAll, b_ih, b_hh, nact, t,
                                         c, hb, hnewAll + (size_t)t * NB * ND, xh_w);
  }
  kPredsAll2<<<dim3(NT, NVPAD / 64), 256, 0, stream>>>(hnewAll, WfcT, b_fc, nact, out_pred);
}